// Round 1
// baseline (4269.497 us; speedup 1.0000x reference)
//
#include <hip/hip_runtime.h>
#include <hip/hip_bf16.h>
#include <math.h>

typedef __attribute__((ext_vector_type(8))) short short8;
typedef __attribute__((ext_vector_type(4))) float floatx4;

#define LRELU_S 0.2f
#define HALF_LOG_2PI 0.91893853320467274178f

__device__ __forceinline__ short f2bf(float f) {
  union { float f; unsigned u; } x; x.f = f;
  unsigned r = x.u + 0x7FFFu + ((x.u >> 16) & 1u);
  return (short)(r >> 16);
}
__device__ __forceinline__ float lrelu(float v) { return v > 0.f ? v : LRELU_S * v; }

__device__ __forceinline__ void atomAddF(float* p, float v) {
  unsafeAtomicAdd(p, v);   // native global_atomic_add_f32 on gfx950
}
__device__ __forceinline__ void atomicMaxF(int* addr, float v) {
  if (v >= 0.f) atomicMax(addr, __float_as_int(v));
  else atomicMin((unsigned int*)addr, __float_as_uint(v));
}

// ============ h = [x | next_demand] ============
__global__ __launch_bounds__(256) void k_concat_h(const float* __restrict__ x,
    const float* __restrict__ nd, float* __restrict__ h, int total) {
  int t = blockIdx.x * 256 + threadIdx.x;
  if (t >= total) return;
  int n = t >> 6, j = t & 63;
  h[t] = (j < 63) ? x[n * 63 + j] : nd[n];
}

// ============ node gemm: out[n][f] = sum_k in[n][k]*W[f][k]; y selects Wl/Wr ============
template<int K, int F>
__global__ __launch_bounds__(256) void k_node_gemm(const float* __restrict__ in,
    const float* __restrict__ Wl, const float* __restrict__ Wr,
    float* __restrict__ xl, float* __restrict__ xr, int n) {
  __shared__ float sx[32][K + 1];
  const int row0 = blockIdx.x * 32;
  const float* __restrict__ W = blockIdx.y ? Wr : Wl;
  float* __restrict__ out = blockIdx.y ? xr : xl;
  const int tid = threadIdx.x;
  for (int i = tid; i < 32 * K; i += 256) {
    int r = i / K, c = i - r * K;
    sx[r][c] = (row0 + r < n) ? in[(size_t)(row0 + r) * K + c] : 0.f;
  }
  __syncthreads();
  const int nl = tid & 31;
  const int fg = tid >> 5;
  const int row = row0 + nl;
  if (row >= n) return;
  constexpr int FP = F / 8;
  for (int i = 0; i < FP; i++) {
    int f = fg * FP + i;
    const float* __restrict__ wrow = W + (size_t)f * K;
    float acc = 0.f;
    #pragma unroll
    for (int k = 0; k < K; k += 4) {
      float4 wv = *(const float4*)(wrow + k);
      acc += sx[nl][k] * wv.x + sx[nl][k + 1] * wv.y
           + sx[nl][k + 2] * wv.z + sx[nl][k + 3] * wv.w;
    }
    out[(size_t)row * F + f] = acc;
  }
}

// ============ GAT pass A: score + segment max ============
template<int H, int C>
__global__ __launch_bounds__(256) void k_gat_score(const float* __restrict__ XL,
    const float* __restrict__ XR, const float* __restrict__ att,
    const int* __restrict__ ei, int E, int Nn, int rev,
    float* __restrict__ SC, int* __restrict__ M) {
  int t = blockIdx.x * 256 + threadIdx.x;
  if (t >= (E + Nn) * H) return;
  int e2 = t / H, h = t - e2 * H;
  int s, d;
  if (e2 < E) { int a = ei[e2], b = ei[E + e2]; s = rev ? b : a; d = rev ? a : b; }
  else { s = d = e2 - E; }
  const float* __restrict__ xlp = XL + (size_t)s * (H * C) + h * C;
  const float* __restrict__ xrp = XR + (size_t)d * (H * C) + h * C;
  const float* __restrict__ ap  = att + h * C;
  float sc = 0.f;
  #pragma unroll
  for (int c = 0; c < C; c += 4) {
    float4 l = *(const float4*)(xlp + c);
    float4 r = *(const float4*)(xrp + c);
    float4 a4 = *(const float4*)(ap + c);
    float v;
    v = l.x + r.x; sc += a4.x * lrelu(v);
    v = l.y + r.y; sc += a4.y * lrelu(v);
    v = l.z + r.z; sc += a4.z * lrelu(v);
    v = l.w + r.w; sc += a4.w * lrelu(v);
  }
  SC[t] = sc;
  atomicMaxF(M + d * H + h, sc);
}

// ============ GAT pass B: denominators ============
template<int H>
__global__ __launch_bounds__(256) void k_gat_den(const float* __restrict__ SC,
    const int* __restrict__ M, float* __restrict__ DEN,
    const int* __restrict__ ei, int E, int Nn, int rev) {
  int t = blockIdx.x * 256 + threadIdx.x;
  if (t >= (E + Nn) * H) return;
  int e2 = t / H, h = t - e2 * H;
  int d;
  if (e2 < E) d = rev ? ei[e2] : ei[E + e2];
  else d = e2 - E;
  float m = __int_as_float(M[d * H + h]);
  atomAddF(DEN + d * H + h, expf(SC[t] - m));
}

// ============ GAT pass C: weighted aggregation ============
template<int H, int C>
__global__ __launch_bounds__(256) void k_gat_agg(const float* __restrict__ XL,
    const float* __restrict__ SC, const int* __restrict__ M,
    const float* __restrict__ DEN, const int* __restrict__ ei,
    int E, int Nn, int rev, float* __restrict__ ACC) {
  int t = blockIdx.x * 256 + threadIdx.x;
  if (t >= (E + Nn) * H) return;
  int e2 = t / H, h = t - e2 * H;
  int s, d;
  if (e2 < E) { int a = ei[e2], b = ei[E + e2]; s = rev ? b : a; d = rev ? a : b; }
  else { s = d = e2 - E; }
  float m = __int_as_float(M[d * H + h]);
  float alpha = expf(SC[t] - m) / (DEN[d * H + h] + 1e-16f);
  const float* __restrict__ xlp = XL + (size_t)s * (H * C) + h * C;
  float* __restrict__ op = ACC + (size_t)d * (H * C) + h * C;
  #pragma unroll
  for (int c = 0; c < C; c++) atomAddF(op + c, alpha * xlp[c]);
}

// ============ node epilogue: y = lrelu(acc + bias) ============
__global__ __launch_bounds__(256) void k_node_ep(const float* __restrict__ ACC,
    const float* __restrict__ bias, float* __restrict__ Y, int total, int fmask) {
  int t = blockIdx.x * 256 + threadIdx.x;
  if (t >= total) return;
  Y[t] = lrelu(ACC[t] + bias[t & fmask]);
}

// ============ s = [xf | xb] -> bf16 ============
__global__ __launch_bounds__(256) void k_concat_s(const float* __restrict__ XF,
    const float* __restrict__ XB, short* __restrict__ SBF, int total) {
  int t = blockIdx.x * 256 + threadIdx.x;
  if (t >= total) return;
  int n = t >> 7, j = t & 127;
  float v = (j < 64) ? XF[n * 64 + j] : XB[n * 64 + (j - 64)];
  SBF[t] = f2bf(v);
}

// ============ weights -> bf16 (Wfc 512x256 | Wfc1 256x512 | Wms 32x256) ============
__global__ __launch_bounds__(256) void k_wconv(const float* __restrict__ Wfc,
    const float* __restrict__ Wfc1, const float* __restrict__ Wmu,
    const float* __restrict__ Wstd, short* __restrict__ WBF) {
  int t = blockIdx.x * 256 + threadIdx.x;
  if (t >= 270336) return;
  float v;
  if (t < 131072) v = Wfc[t];
  else if (t < 262144) v = Wfc1[t - 131072];
  else {
    int u = t - 262144;
    int r = u >> 8, c = u & 255;
    v = (r < 16) ? Wmu[r * 256 + c] : Wstd[(r - 16) * 256 + c];
  }
  WBF[t] = f2bf(v);
}

// ============ fused MLP head: 32 edges / block, bf16 MFMA ============
__device__ __forceinline__ short8 lds_frag(const char* base, int row, int strideB, int k0, int lg) {
  int off = row * strideB + (((k0 * 2) + lg * 16) ^ ((row & 7) << 4));
  return *(const short8*)(base + off);
}

__global__ __launch_bounds__(256) void k_head(
    const short* __restrict__ SBF, const short* __restrict__ WBF,
    const int* __restrict__ ei, const float* __restrict__ epsg,
    const float* __restrict__ b_fc, const float* __restrict__ b_fc1,
    const float* __restrict__ b_mu, const float* __restrict__ b_std,
    float* __restrict__ out, double* __restrict__ LP, int E) {
  __shared__ __align__(16) char lX[32 * 512];    // X [32][256] bf16; reused as H2 [32][256]
  __shared__ __align__(16) char lH1[32 * 1024];  // H1 [32][512] bf16
  __shared__ float lMS[32 * 32];
  __shared__ float lred[4];

  const int tid = threadIdx.x;
  const int eg0 = blockIdx.x * 32;

  // gather X rows = [s[e0] | s[e1]] with write-side swizzle
  for (int q = tid; q < 1024; q += 256) {
    int le = q >> 5, c = q & 31;
    int eg = eg0 + le;
    int node = (c < 16) ? ei[eg] : ei[E + eg];
    const short* srcp = SBF + (size_t)node * 128 + (c & 15) * 8;
    int4 v = *(const int4*)srcp;
    int col = (c * 16) ^ ((le & 7) << 4);
    *(int4*)(lX + le * 512 + col) = v;
  }
  __syncthreads();

  const int w = tid >> 6, lane = tid & 63;
  const int lr = lane & 15, lg = lane >> 4;
  const floatx4 zero = {0.f, 0.f, 0.f, 0.f};

  // ---- layer 1: X[32,256] @ Wfc^T -> H1[32,512]; wave handles n-range [w*128, w*128+128)
  floatx4 acc1[2][8];
  #pragma unroll
  for (int mi = 0; mi < 2; mi++)
    #pragma unroll
    for (int ni = 0; ni < 8; ni++) acc1[mi][ni] = zero;
  const short* __restrict__ Wfc = WBF;             // [512][256]
  for (int kk = 0; kk < 8; kk++) {
    int k0 = kk * 32;
    short8 a0 = lds_frag(lX, lr, 512, k0, lg);
    short8 a1 = lds_frag(lX, 16 + lr, 512, k0, lg);
    #pragma unroll
    for (int ni = 0; ni < 8; ni++) {
      int nn = w * 128 + ni * 16 + lr;
      short8 b = *(const short8*)(Wfc + (size_t)nn * 256 + k0 + lg * 8);
      acc1[0][ni] = __builtin_amdgcn_mfma_f32_16x16x32_bf16(a0, b, acc1[0][ni], 0, 0, 0);
      acc1[1][ni] = __builtin_amdgcn_mfma_f32_16x16x32_bf16(a1, b, acc1[1][ni], 0, 0, 0);
    }
  }
  #pragma unroll
  for (int mi = 0; mi < 2; mi++)
    #pragma unroll
    for (int ni = 0; ni < 8; ni++) {
      int coln = w * 128 + ni * 16 + lr;
      float bv = b_fc[coln];
      #pragma unroll
      for (int j = 0; j < 4; j++) {
        int row = mi * 16 + lg * 4 + j;
        float v = acc1[mi][ni][j] + bv;
        v = v > 0.f ? v : 0.f;
        *(short*)(lH1 + row * 1024 + ((coln * 2) ^ ((row & 7) << 4))) = f2bf(v);
      }
    }
  __syncthreads();

  // ---- layer 2: H1[32,512] @ Wfc1^T -> H2[32,256] (into lX); wave n-range [w*64, w*64+64)
  floatx4 acc2[2][4];
  #pragma unroll
  for (int mi = 0; mi < 2; mi++)
    #pragma unroll
    for (int ni = 0; ni < 4; ni++) acc2[mi][ni] = zero;
  const short* __restrict__ Wfc1 = WBF + 131072;   // [256][512]
  for (int kk = 0; kk < 16; kk++) {
    int k0 = kk * 32;
    short8 a0 = lds_frag(lH1, lr, 1024, k0, lg);
    short8 a1 = lds_frag(lH1, 16 + lr, 1024, k0, lg);
    #pragma unroll
    for (int ni = 0; ni < 4; ni++) {
      int nn = w * 64 + ni * 16 + lr;
      short8 b = *(const short8*)(Wfc1 + (size_t)nn * 512 + k0 + lg * 8);
      acc2[0][ni] = __builtin_amdgcn_mfma_f32_16x16x32_bf16(a0, b, acc2[0][ni], 0, 0, 0);
      acc2[1][ni] = __builtin_amdgcn_mfma_f32_16x16x32_bf16(a1, b, acc2[1][ni], 0, 0, 0);
    }
  }
  __syncthreads();   // everyone done reading lX (layer1) and lH1 writes are done
  #pragma unroll
  for (int mi = 0; mi < 2; mi++)
    #pragma unroll
    for (int ni = 0; ni < 4; ni++) {
      int coln = w * 64 + ni * 16 + lr;
      float bv = b_fc1[coln];
      #pragma unroll
      for (int j = 0; j < 4; j++) {
        int row = mi * 16 + lg * 4 + j;
        float v = acc2[mi][ni][j] + bv;
        v = v > 0.f ? v : 0.f;
        *(short*)(lX + row * 512 + ((coln * 2) ^ ((row & 7) << 4))) = f2bf(v);
      }
    }
  __syncthreads();

  // ---- layer 3: H2[32,256] @ Wms^T[32,256] -> MS[32,32]; wave w: mfrag=w&1, nfrag=w>>1
  const short* __restrict__ Wms = WBF + 262144;    // [32][256]
  const int mfr = w & 1, nfr = w >> 1;
  floatx4 acc3 = zero;
  for (int kk = 0; kk < 8; kk++) {
    int k0 = kk * 32;
    short8 a = lds_frag(lX, mfr * 16 + lr, 512, k0, lg);
    short8 b = *(const short8*)(Wms + (size_t)(nfr * 16 + lr) * 256 + k0 + lg * 8);
    acc3 = __builtin_amdgcn_mfma_f32_16x16x32_bf16(a, b, acc3, 0, 0, 0);
  }
  {
    int coln = nfr * 16 + lr;
    float bv = (coln < 16) ? b_mu[coln] : b_std[coln - 16];
    #pragma unroll
    for (int j = 0; j < 4; j++) {
      int row = mfr * 16 + lg * 4 + j;
      lMS[row * 32 + coln] = acc3[j] + bv;
    }
  }
  __syncthreads();

  // ---- epilogue: sample, tanh, log-prob partial
  float lpsum = 0.f;
  #pragma unroll
  for (int it = 0; it < 2; it++) {
    int idx = tid + it * 256;
    int m = idx >> 4, g = idx & 15;
    float mu = lMS[m * 32 + g];
    float sr = lMS[m * 32 + 16 + g];
    float sd = (sr > 20.f) ? sr : log1pf(expf(sr));
    int eg = eg0 + m;
    float ep = epsg[(size_t)eg * 16 + g];
    float action = mu + sd * ep;
    float ra = tanhf(action);
    out[(size_t)eg * 16 + g] = ra;
    lpsum += -0.5f * ep * ep - logf(sd) - HALF_LOG_2PI - logf(1.f - ra * ra + 1e-7f);
  }
  #pragma unroll
  for (int o = 32; o > 0; o >>= 1) lpsum += __shfl_xor(lpsum, o, 64);
  if (lane == 0) lred[w] = lpsum;
  __syncthreads();
  if (tid == 0) {
    double ssum = (double)lred[0] + (double)lred[1] + (double)lred[2] + (double)lred[3];
    atomicAdd(LP, ssum);
  }
}

__global__ void k_finalize(const double* __restrict__ LP, float* __restrict__ out, int pos) {
  out[pos] = (float)(*LP);
}

// =====================================================================
extern "C" void kernel_launch(void* const* d_in, const int* in_sizes, int n_in,
                              void* d_out, int out_size, void* d_ws, size_t ws_size,
                              hipStream_t stream) {
  const float* x    = (const float*)d_in[0];
  const float* nd   = (const float*)d_in[1];
  const int*   ei   = (const int*)d_in[2];
  const float* epsg = (const float*)d_in[3];
  const float* Wl3 = (const float*)d_in[4];  const float* Wr3 = (const float*)d_in[5];
  const float* att3 = (const float*)d_in[6]; const float* b3 = (const float*)d_in[7];
  const float* Wl4 = (const float*)d_in[8];  const float* Wr4 = (const float*)d_in[9];
  const float* att4 = (const float*)d_in[10]; const float* b4 = (const float*)d_in[11];
  const float* Wl1 = (const float*)d_in[12]; const float* Wr1 = (const float*)d_in[13];
  const float* att1 = (const float*)d_in[14]; const float* b1 = (const float*)d_in[15];
  const float* Wl2 = (const float*)d_in[16]; const float* Wr2 = (const float*)d_in[17];
  const float* att2 = (const float*)d_in[18]; const float* b2 = (const float*)d_in[19];
  const float* W_fc  = (const float*)d_in[20]; const float* b_fc  = (const float*)d_in[21];
  const float* W_fc1 = (const float*)d_in[22]; const float* b_fc1 = (const float*)d_in[23];
  const float* W_mu  = (const float*)d_in[24]; const float* b_mu  = (const float*)d_in[25];
  const float* W_std = (const float*)d_in[26]; const float* b_std = (const float*)d_in[27];

  const int N = in_sizes[0] / 63;
  const int E = in_sizes[2] / 2;
  const int E2 = E + N;
  const size_t NN = (size_t)N;

  float* ws   = (float*)d_ws;
  float* bufA = ws;                    // [N,128] (h uses first 64 cols packed as [N,64])
  float* bufB = bufA + NN * 128;       // [N,128]
  float* XL   = bufB + NN * 128;
  float* XR   = XL + NN * 128;
  float* ACC  = XR + NN * 128;
  float* XBp  = ACC + NN * 128;        // [N,64]
  float* XFp  = XBp + NN * 64;         // [N,64]
  float* Mf   = XFp + NN * 64;         // [N*4] int bits
  float* DENp = Mf + NN * 4;           // [N*4]
  float* SCp  = DENp + NN * 4;         // [E2*4]
  size_t off = (size_t)(SCp + (size_t)E2 * 4 - ws);
  off = (off + 3) & ~(size_t)3;        // 16B align
  double* LPp = (double*)(ws + off);
  off += 4;
  short* SBF = (short*)(ws + off);     // N*128 bf16
  off += NN * 64;
  short* WBF = (short*)(ws + off);     // 270336 bf16

  auto nb = [](int total) { return (total + 255) / 256; };

  k_concat_h<<<nb(N * 64), 256, 0, stream>>>(x, nd, bufA, N * 64);
  k_wconv<<<nb(270336), 256, 0, stream>>>(W_fc, W_fc1, W_mu, W_std, WBF);

  // ---- gat3: h[N,64] -> bufB[N,128], reversed edges, H=4 C=32
  hipMemsetAsync(ACC, 0, NN * 128 * 4, stream);
  hipMemsetAsync(DENp, 0, NN * 16, stream);
  hipMemsetAsync(Mf, 0xFF, NN * 16, stream);
  { dim3 g((N + 31) / 32, 2);
    k_node_gemm<64, 128><<<g, 256, 0, stream>>>(bufA, Wl3, Wr3, XL, XR, N); }
  k_gat_score<4, 32><<<nb(E2 * 4), 256, 0, stream>>>(XL, XR, att3, ei, E, N, 1, SCp, (int*)Mf);
  k_gat_den<4><<<nb(E2 * 4), 256, 0, stream>>>(SCp, (int*)Mf, DENp, ei, E, N, 1);
  k_gat_agg<4, 32><<<nb(E2 * 4), 256, 0, stream>>>(XL, SCp, (int*)Mf, DENp, ei, E, N, 1, ACC);
  k_node_ep<<<nb(N * 128), 256, 0, stream>>>(ACC, b3, bufB, N * 128, 127);

  // ---- gat4: bufB[N,128] -> XB[N,64], reversed edges, H=1 C=64
  hipMemsetAsync(ACC, 0, NN * 64 * 4, stream);
  hipMemsetAsync(DENp, 0, NN * 4, stream);
  hipMemsetAsync(Mf, 0xFF, NN * 4, stream);
  { dim3 g((N + 31) / 32, 2);
    k_node_gemm<128, 64><<<g, 256, 0, stream>>>(bufB, Wl4, Wr4, XL, XR, N); }
  k_gat_score<1, 64><<<nb(E2), 256, 0, stream>>>(XL, XR, att4, ei, E, N, 1, SCp, (int*)Mf);
  k_gat_den<1><<<nb(E2), 256, 0, stream>>>(SCp, (int*)Mf, DENp, ei, E, N, 1);
  k_gat_agg<1, 64><<<nb(E2), 256, 0, stream>>>(XL, SCp, (int*)Mf, DENp, ei, E, N, 1, ACC);
  k_node_ep<<<nb(N * 64), 256, 0, stream>>>(ACC, b4, XBp, N * 64, 63);

  // ---- gat1: XB[N,64] -> bufB[N,128], forward edges, H=4 C=32
  hipMemsetAsync(ACC, 0, NN * 128 * 4, stream);
  hipMemsetAsync(DENp, 0, NN * 16, stream);
  hipMemsetAsync(Mf, 0xFF, NN * 16, stream);
  { dim3 g((N + 31) / 32, 2);
    k_node_gemm<64, 128><<<g, 256, 0, stream>>>(XBp, Wl1, Wr1, XL, XR, N); }
  k_gat_score<4, 32><<<nb(E2 * 4), 256, 0, stream>>>(XL, XR, att1, ei, E, N, 0, SCp, (int*)Mf);
  k_gat_den<4><<<nb(E2 * 4), 256, 0, stream>>>(SCp, (int*)Mf, DENp, ei, E, N, 0);
  k_gat_agg<4, 32><<<nb(E2 * 4), 256, 0, stream>>>(XL, SCp, (int*)Mf, DENp, ei, E, N, 0, ACC);
  k_node_ep<<<nb(N * 128), 256, 0, stream>>>(ACC, b1, bufB, N * 128, 127);

  // ---- gat2: bufB[N,128] -> XF[N,64], forward edges, H=1 C=64
  hipMemsetAsync(ACC, 0, NN * 64 * 4, stream);
  hipMemsetAsync(DENp, 0, NN * 4, stream);
  hipMemsetAsync(Mf, 0xFF, NN * 4, stream);
  { dim3 g((N + 31) / 32, 2);
    k_node_gemm<128, 64><<<g, 256, 0, stream>>>(bufB, Wl2, Wr2, XL, XR, N); }
  k_gat_score<1, 64><<<nb(E2), 256, 0, stream>>>(XL, XR, att2, ei, E, N, 0, SCp, (int*)Mf);
  k_gat_den<1><<<nb(E2), 256, 0, stream>>>(SCp, (int*)Mf, DENp, ei, E, N, 0);
  k_gat_agg<1, 64><<<nb(E2), 256, 0, stream>>>(XL, SCp, (int*)Mf, DENp, ei, E, N, 0, ACC);
  k_node_ep<<<nb(N * 64), 256, 0, stream>>>(ACC, b2, XFp, N * 64, 63);

  // ---- head
  k_concat_s<<<nb(N * 128), 256, 0, stream>>>(XFp, XBp, SBF, N * 128);
  hipMemsetAsync(LPp, 0, 8, stream);
  k_head<<<E / 32, 256, 0, stream>>>(SBF, WBF, ei, epsg, b_fc, b_fc1, b_mu, b_std,
                                     (float*)d_out, LPp, E);
  k_finalize<<<1, 1, 0, stream>>>(LPp, (float*)d_out, E * 16);
}

// Round 2
// 820.357 us; speedup vs baseline: 5.2044x; 5.2044x over previous
//
#include <hip/hip_runtime.h>
#include <hip/hip_bf16.h>
#include <math.h>

typedef __attribute__((ext_vector_type(8))) short short8;
typedef __attribute__((ext_vector_type(4))) float floatx4;

#define LRELU_S 0.2f
#define HALF_LOG_2PI 0.91893853320467274178f

__device__ __forceinline__ short f2bf(float f) {
  union { float f; unsigned u; } x; x.f = f;
  unsigned r = x.u + 0x7FFFu + ((x.u >> 16) & 1u);
  return (short)(r >> 16);
}
__device__ __forceinline__ float lrelu(float v) { return v > 0.f ? v : LRELU_S * v; }

// ============ h = [x | next_demand] ============
__global__ __launch_bounds__(256) void k_concat_h(const float* __restrict__ x,
    const float* __restrict__ nd, float* __restrict__ h, int total) {
  int t = blockIdx.x * 256 + threadIdx.x;
  if (t >= total) return;
  int n = t >> 6, j = t & 63;
  h[t] = (j < 63) ? x[n * 63 + j] : nd[n];
}

// ============ CSR build ============
__global__ __launch_bounds__(256) void k_deg(const int* __restrict__ ei,
    int* __restrict__ degF, int* __restrict__ degR, int E) {
  int e = blockIdx.x * 256 + threadIdx.x;
  if (e >= E) return;
  int a = ei[e], b = ei[E + e];        // a=ei[0], b=ei[1]
  atomicAdd(degF + b, 1);              // forward: dst = ei[1]
  atomicAdd(degR + a, 1);              // reverse: dst = ei[0]
}

__global__ __launch_bounds__(256) void k_scan(const int* __restrict__ deg,
    int* __restrict__ start, int* __restrict__ cur, int n) {
  __shared__ int part[256];
  int chunk = (n + 255) / 256;
  int t = threadIdx.x;
  int lo = t * chunk, hi = min(lo + chunk, n);
  int s = 0;
  for (int i = lo; i < hi; i++) s += deg[i] + 1;   // +1 self-loop slot
  part[t] = s;
  __syncthreads();
  if (t == 0) {
    int acc = 0;
    for (int i = 0; i < 256; i++) { int v = part[i]; part[i] = acc; acc += v; }
    start[n] = acc;
  }
  __syncthreads();
  int acc = part[t];
  for (int i = lo; i < hi; i++) {
    start[i] = acc; cur[i] = acc;
    acc += deg[i] + 1;
  }
}

__global__ __launch_bounds__(256) void k_scatter(const int* __restrict__ ei,
    int* __restrict__ curF, int* __restrict__ curR,
    int* __restrict__ csrF, int* __restrict__ csrR, int E) {
  int e = blockIdx.x * 256 + threadIdx.x;
  if (e >= E) return;
  int a = ei[e], b = ei[E + e];
  int pf = atomicAdd(curF + b, 1); csrF[pf] = a;   // fwd: dst=b stores src=a
  int pr = atomicAdd(curR + a, 1); csrR[pr] = b;   // rev: dst=a stores src=b
}

__global__ __launch_bounds__(256) void k_self(const int* __restrict__ startF,
    const int* __restrict__ startR, int* __restrict__ csrF, int* __restrict__ csrR, int n) {
  int d = blockIdx.x * 256 + threadIdx.x;
  if (d >= n) return;
  csrF[startF[d + 1] - 1] = d;
  csrR[startR[d + 1] - 1] = d;
}

// ============ node gemm: out[n][f] = sum_k in[n][k]*W[f][k] ============
template<int K, int F>
__global__ __launch_bounds__(256) void k_node_gemm(const float* __restrict__ in,
    const float* __restrict__ Wl, const float* __restrict__ Wr,
    float* __restrict__ xl, float* __restrict__ xr, int n) {
  __shared__ float sx[32][K + 1];
  const int row0 = blockIdx.x * 32;
  const float* __restrict__ W = blockIdx.y ? Wr : Wl;
  float* __restrict__ out = blockIdx.y ? xr : xl;
  const int tid = threadIdx.x;
  for (int i = tid; i < 32 * K; i += 256) {
    int r = i / K, c = i - r * K;
    sx[r][c] = (row0 + r < n) ? in[(size_t)(row0 + r) * K + c] : 0.f;
  }
  __syncthreads();
  const int nl = tid & 31;
  const int fg = tid >> 5;
  const int row = row0 + nl;
  if (row >= n) return;
  constexpr int FP = F / 8;
  for (int i = 0; i < FP; i++) {
    int f = fg * FP + i;
    const float* __restrict__ wrow = W + (size_t)f * K;
    float acc = 0.f;
    #pragma unroll
    for (int k = 0; k < K; k += 4) {
      float4 wv = *(const float4*)(wrow + k);
      acc += sx[nl][k] * wv.x + sx[nl][k + 1] * wv.y
           + sx[nl][k + 2] * wv.z + sx[nl][k + 3] * wv.w;
    }
    out[(size_t)row * F + f] = acc;
  }
}

// ============ fused GATv2 edge pass: score + online softmax + agg + bias + lrelu ============
// HF = heads*channels (output width), C = channels per head (reduce width).
// One HF-thread group per dst; thread = one feature f = h*C + c.
template<int HF, int C>
__global__ __launch_bounds__(256) void k_gat_fused(const float* __restrict__ XL,
    const float* __restrict__ XR, const float* __restrict__ att,
    const float* __restrict__ bias, const int* __restrict__ start,
    const int* __restrict__ csr, float* __restrict__ out, int n) {
  constexpr int DPB = 256 / HF;
  int d = blockIdx.x * DPB + threadIdx.x / HF;
  if (d >= n) return;
  int f = threadIdx.x & (HF - 1);
  float xr = XR[(size_t)d * HF + f];
  float av = att[f];
  float m = -INFINITY, den = 0.f, acc = 0.f;
  int j1 = start[d + 1];
  for (int j = start[d]; j < j1; j++) {
    int s = csr[j];
    float xl = XL[(size_t)s * HF + f];
    float e = xl + xr;
    e = e > 0.f ? e : LRELU_S * e;
    float partial = av * e;
    #pragma unroll
    for (int o = C / 2; o > 0; o >>= 1) partial += __shfl_xor(partial, o, 64);
    float sc = partial;                 // same in all C lanes of the head
    float mn = fmaxf(m, sc);
    float scale = expf(m - mn);         // first iter: exp(-inf)=0
    float p = expf(sc - mn);
    den = den * scale + p;
    acc = acc * scale + p * xl;
    m = mn;
  }
  out[(size_t)d * HF + f] = lrelu(acc / (den + 1e-16f) + bias[f]);
}

// ============ s = [xf | xb] -> bf16 ============
__global__ __launch_bounds__(256) void k_concat_s(const float* __restrict__ XF,
    const float* __restrict__ XB, short* __restrict__ SBF, int total) {
  int t = blockIdx.x * 256 + threadIdx.x;
  if (t >= total) return;
  int n = t >> 7, j = t & 127;
  float v = (j < 64) ? XF[n * 64 + j] : XB[n * 64 + (j - 64)];
  SBF[t] = f2bf(v);
}

// ============ weights -> bf16 (Wfc 512x256 | Wfc1 256x512 | Wms 32x256) ============
__global__ __launch_bounds__(256) void k_wconv(const float* __restrict__ Wfc,
    const float* __restrict__ Wfc1, const float* __restrict__ Wmu,
    const float* __restrict__ Wstd, short* __restrict__ WBF) {
  int t = blockIdx.x * 256 + threadIdx.x;
  if (t >= 270336) return;
  float v;
  if (t < 131072) v = Wfc[t];
  else if (t < 262144) v = Wfc1[t - 131072];
  else {
    int u = t - 262144;
    int r = u >> 8, c = u & 255;
    v = (r < 16) ? Wmu[r * 256 + c] : Wstd[(r - 16) * 256 + c];
  }
  WBF[t] = f2bf(v);
}

// ============ fused MLP head: 32 edges / block, bf16 MFMA ============
__device__ __forceinline__ short8 lds_frag(const char* base, int row, int strideB, int k0, int lg) {
  int off = row * strideB + (((k0 * 2) + lg * 16) ^ ((row & 7) << 4));
  return *(const short8*)(base + off);
}

__global__ __launch_bounds__(256) void k_head(
    const short* __restrict__ SBF, const short* __restrict__ WBF,
    const int* __restrict__ ei, const float* __restrict__ epsg,
    const float* __restrict__ b_fc, const float* __restrict__ b_fc1,
    const float* __restrict__ b_mu, const float* __restrict__ b_std,
    float* __restrict__ out, double* __restrict__ LP, int E) {
  __shared__ __align__(16) char lX[32 * 512];    // X [32][256] bf16; reused as H2 [32][256]
  __shared__ __align__(16) char lH1[32 * 1024];  // H1 [32][512] bf16
  __shared__ float lMS[32 * 32];
  __shared__ float lred[4];

  const int tid = threadIdx.x;
  const int eg0 = blockIdx.x * 32;

  for (int q = tid; q < 1024; q += 256) {
    int le = q >> 5, c = q & 31;
    int eg = eg0 + le;
    int node = (c < 16) ? ei[eg] : ei[E + eg];
    const short* srcp = SBF + (size_t)node * 128 + (c & 15) * 8;
    int4 v = *(const int4*)srcp;
    int col = (c * 16) ^ ((le & 7) << 4);
    *(int4*)(lX + le * 512 + col) = v;
  }
  __syncthreads();

  const int w = tid >> 6, lane = tid & 63;
  const int lr = lane & 15, lg = lane >> 4;
  const floatx4 zero = {0.f, 0.f, 0.f, 0.f};

  // ---- layer 1: X[32,256] @ Wfc^T -> H1[32,512]
  floatx4 acc1[2][8];
  #pragma unroll
  for (int mi = 0; mi < 2; mi++)
    #pragma unroll
    for (int ni = 0; ni < 8; ni++) acc1[mi][ni] = zero;
  const short* __restrict__ Wfc = WBF;             // [512][256]
  for (int kk = 0; kk < 8; kk++) {
    int k0 = kk * 32;
    short8 a0 = lds_frag(lX, lr, 512, k0, lg);
    short8 a1 = lds_frag(lX, 16 + lr, 512, k0, lg);
    #pragma unroll
    for (int ni = 0; ni < 8; ni++) {
      int nn = w * 128 + ni * 16 + lr;
      short8 b = *(const short8*)(Wfc + (size_t)nn * 256 + k0 + lg * 8);
      acc1[0][ni] = __builtin_amdgcn_mfma_f32_16x16x32_bf16(a0, b, acc1[0][ni], 0, 0, 0);
      acc1[1][ni] = __builtin_amdgcn_mfma_f32_16x16x32_bf16(a1, b, acc1[1][ni], 0, 0, 0);
    }
  }
  #pragma unroll
  for (int mi = 0; mi < 2; mi++)
    #pragma unroll
    for (int ni = 0; ni < 8; ni++) {
      int coln = w * 128 + ni * 16 + lr;
      float bv = b_fc[coln];
      #pragma unroll
      for (int j = 0; j < 4; j++) {
        int row = mi * 16 + lg * 4 + j;
        float v = acc1[mi][ni][j] + bv;
        v = v > 0.f ? v : 0.f;
        *(short*)(lH1 + row * 1024 + ((coln * 2) ^ ((row & 7) << 4))) = f2bf(v);
      }
    }
  __syncthreads();

  // ---- layer 2: H1[32,512] @ Wfc1^T -> H2[32,256] (into lX)
  floatx4 acc2[2][4];
  #pragma unroll
  for (int mi = 0; mi < 2; mi++)
    #pragma unroll
    for (int ni = 0; ni < 4; ni++) acc2[mi][ni] = zero;
  const short* __restrict__ Wfc1 = WBF + 131072;   // [256][512]
  for (int kk = 0; kk < 16; kk++) {
    int k0 = kk * 32;
    short8 a0 = lds_frag(lH1, lr, 1024, k0, lg);
    short8 a1 = lds_frag(lH1, 16 + lr, 1024, k0, lg);
    #pragma unroll
    for (int ni = 0; ni < 4; ni++) {
      int nn = w * 64 + ni * 16 + lr;
      short8 b = *(const short8*)(Wfc1 + (size_t)nn * 512 + k0 + lg * 8);
      acc2[0][ni] = __builtin_amdgcn_mfma_f32_16x16x32_bf16(a0, b, acc2[0][ni], 0, 0, 0);
      acc2[1][ni] = __builtin_amdgcn_mfma_f32_16x16x32_bf16(a1, b, acc2[1][ni], 0, 0, 0);
    }
  }
  __syncthreads();
  #pragma unroll
  for (int mi = 0; mi < 2; mi++)
    #pragma unroll
    for (int ni = 0; ni < 4; ni++) {
      int coln = w * 64 + ni * 16 + lr;
      float bv = b_fc1[coln];
      #pragma unroll
      for (int j = 0; j < 4; j++) {
        int row = mi * 16 + lg * 4 + j;
        float v = acc2[mi][ni][j] + bv;
        v = v > 0.f ? v : 0.f;
        *(short*)(lX + row * 512 + ((coln * 2) ^ ((row & 7) << 4))) = f2bf(v);
      }
    }
  __syncthreads();

  // ---- layer 3: H2[32,256] @ Wms^T[32,256] -> MS[32,32]
  const short* __restrict__ Wms = WBF + 262144;    // [32][256]
  const int mfr = w & 1, nfr = w >> 1;
  floatx4 acc3 = zero;
  for (int kk = 0; kk < 8; kk++) {
    int k0 = kk * 32;
    short8 a = lds_frag(lX, mfr * 16 + lr, 512, k0, lg);
    short8 b = *(const short8*)(Wms + (size_t)(nfr * 16 + lr) * 256 + k0 + lg * 8);
    acc3 = __builtin_amdgcn_mfma_f32_16x16x32_bf16(a, b, acc3, 0, 0, 0);
  }
  {
    int coln = nfr * 16 + lr;
    float bv = (coln < 16) ? b_mu[coln] : b_std[coln - 16];
    #pragma unroll
    for (int j = 0; j < 4; j++) {
      int row = mfr * 16 + lg * 4 + j;
      lMS[row * 32 + coln] = acc3[j] + bv;
    }
  }
  __syncthreads();

  // ---- epilogue: sample, tanh, log-prob partial
  float lpsum = 0.f;
  #pragma unroll
  for (int it = 0; it < 2; it++) {
    int idx = tid + it * 256;
    int m = idx >> 4, g = idx & 15;
    float mu = lMS[m * 32 + g];
    float sr = lMS[m * 32 + 16 + g];
    float sd = (sr > 20.f) ? sr : log1pf(expf(sr));
    int eg = eg0 + m;
    float ep = epsg[(size_t)eg * 16 + g];
    float action = mu + sd * ep;
    float ra = tanhf(action);
    out[(size_t)eg * 16 + g] = ra;
    lpsum += -0.5f * ep * ep - logf(sd) - HALF_LOG_2PI - logf(1.f - ra * ra + 1e-7f);
  }
  #pragma unroll
  for (int o = 32; o > 0; o >>= 1) lpsum += __shfl_xor(lpsum, o, 64);
  if (lane == 0) lred[w] = lpsum;
  __syncthreads();
  if (tid == 0) {
    double ssum = (double)lred[0] + (double)lred[1] + (double)lred[2] + (double)lred[3];
    atomicAdd(LP, ssum);
  }
}

__global__ void k_finalize(const double* __restrict__ LP, float* __restrict__ out, int pos) {
  out[pos] = (float)(*LP);
}

// =====================================================================
extern "C" void kernel_launch(void* const* d_in, const int* in_sizes, int n_in,
                              void* d_out, int out_size, void* d_ws, size_t ws_size,
                              hipStream_t stream) {
  const float* x    = (const float*)d_in[0];
  const float* nd   = (const float*)d_in[1];
  const int*   ei   = (const int*)d_in[2];
  const float* epsg = (const float*)d_in[3];
  const float* Wl3 = (const float*)d_in[4];  const float* Wr3 = (const float*)d_in[5];
  const float* att3 = (const float*)d_in[6]; const float* b3 = (const float*)d_in[7];
  const float* Wl4 = (const float*)d_in[8];  const float* Wr4 = (const float*)d_in[9];
  const float* att4 = (const float*)d_in[10]; const float* b4 = (const float*)d_in[11];
  const float* Wl1 = (const float*)d_in[12]; const float* Wr1 = (const float*)d_in[13];
  const float* att1 = (const float*)d_in[14]; const float* b1 = (const float*)d_in[15];
  const float* Wl2 = (const float*)d_in[16]; const float* Wr2 = (const float*)d_in[17];
  const float* att2 = (const float*)d_in[18]; const float* b2 = (const float*)d_in[19];
  const float* W_fc  = (const float*)d_in[20]; const float* b_fc  = (const float*)d_in[21];
  const float* W_fc1 = (const float*)d_in[22]; const float* b_fc1 = (const float*)d_in[23];
  const float* W_mu  = (const float*)d_in[24]; const float* b_mu  = (const float*)d_in[25];
  const float* W_std = (const float*)d_in[26]; const float* b_std = (const float*)d_in[27];

  const int N = in_sizes[0] / 63;
  const int E = in_sizes[2] / 2;
  const int E2 = E + N;
  const size_t NN = (size_t)N;

  char* base = (char*)d_ws;
  auto alloc = [&](size_t bytes) { char* p = base; base += (bytes + 15) & ~(size_t)15; return p; };

  float* bufA = (float*)alloc(NN * 128 * 4);
  float* bufB = (float*)alloc(NN * 128 * 4);
  float* XL   = (float*)alloc(NN * 128 * 4);
  float* XR   = (float*)alloc(NN * 128 * 4);
  float* XBp  = (float*)alloc(NN * 64 * 4);
  float* XFp  = (float*)alloc(NN * 64 * 4);
  int* degF   = (int*)alloc(NN * 4);
  int* degR   = (int*)alloc(NN * 4);
  int* curF   = (int*)alloc(NN * 4);
  int* curR   = (int*)alloc(NN * 4);
  int* startF = (int*)alloc((NN + 1) * 4);
  int* startR = (int*)alloc((NN + 1) * 4);
  int* csrF   = (int*)alloc((size_t)E2 * 4);
  int* csrR   = (int*)alloc((size_t)E2 * 4);
  double* LPp = (double*)alloc(8);
  short* SBF  = (short*)alloc(NN * 128 * 2);
  short* WBF  = (short*)alloc(270336 * 2);

  auto nb = [](int total) { return (total + 255) / 256; };

  // ---- CSR build (both directions)
  hipMemsetAsync(degF, 0, NN * 4, stream);
  hipMemsetAsync(degR, 0, NN * 4, stream);
  k_deg<<<nb(E), 256, 0, stream>>>(ei, degF, degR, E);
  k_scan<<<1, 256, 0, stream>>>(degF, startF, curF, N);
  k_scan<<<1, 256, 0, stream>>>(degR, startR, curR, N);
  k_scatter<<<nb(E), 256, 0, stream>>>(ei, curF, curR, csrF, csrR, E);
  k_self<<<nb(N), 256, 0, stream>>>(startF, startR, csrF, csrR, N);

  k_concat_h<<<nb(N * 64), 256, 0, stream>>>(x, nd, bufA, N * 64);
  k_wconv<<<nb(270336), 256, 0, stream>>>(W_fc, W_fc1, W_mu, W_std, WBF);

  // ---- gat3 (reverse): h[N,64] -> bufB[N,128]
  { dim3 g((N + 31) / 32, 2);
    k_node_gemm<64, 128><<<g, 256, 0, stream>>>(bufA, Wl3, Wr3, XL, XR, N); }
  k_gat_fused<128, 32><<<(N + 1) / 2, 256, 0, stream>>>(XL, XR, att3, b3, startR, csrR, bufB, N);

  // ---- gat4 (reverse): bufB[N,128] -> XB[N,64]
  { dim3 g((N + 31) / 32, 2);
    k_node_gemm<128, 64><<<g, 256, 0, stream>>>(bufB, Wl4, Wr4, XL, XR, N); }
  k_gat_fused<64, 64><<<(N + 3) / 4, 256, 0, stream>>>(XL, XR, att4, b4, startR, csrR, XBp, N);

  // ---- gat1 (forward): XB[N,64] -> bufB[N,128]
  { dim3 g((N + 31) / 32, 2);
    k_node_gemm<64, 128><<<g, 256, 0, stream>>>(XBp, Wl1, Wr1, XL, XR, N); }
  k_gat_fused<128, 32><<<(N + 1) / 2, 256, 0, stream>>>(XL, XR, att1, b1, startF, csrF, bufB, N);

  // ---- gat2 (forward): bufB[N,128] -> XF[N,64]
  { dim3 g((N + 31) / 32, 2);
    k_node_gemm<128, 64><<<g, 256, 0, stream>>>(bufB, Wl2, Wr2, XL, XR, N); }
  k_gat_fused<64, 64><<<(N + 3) / 4, 256, 0, stream>>>(XL, XR, att2, b2, startF, csrF, XFp, N);

  // ---- head
  k_concat_s<<<nb(N * 128), 256, 0, stream>>>(XFp, XBp, SBF, N * 128);
  hipMemsetAsync(LPp, 0, 8, stream);
  k_head<<<E / 32, 256, 0, stream>>>(SBF, WBF, ei, epsg, b_fc, b_fc1, b_mu, b_std,
                                     (float*)d_out, LPp, E);
  k_finalize<<<1, 1, 0, stream>>>(LPp, (float*)d_out, E * 16);
}

// Round 3
// 596.793 us; speedup vs baseline: 7.1541x; 1.3746x over previous
//
#include <hip/hip_runtime.h>
#include <hip/hip_bf16.h>
#include <math.h>

typedef __attribute__((ext_vector_type(8))) short short8;
typedef __attribute__((ext_vector_type(4))) float floatx4;

#define LRELU_S 0.2f
#define HALF_LOG_2PI 0.91893853320467274178f

__device__ __forceinline__ short f2bf(float f) {
  union { float f; unsigned u; } x; x.f = f;
  unsigned r = x.u + 0x7FFFu + ((x.u >> 16) & 1u);
  return (short)(r >> 16);
}
__device__ __forceinline__ float lrelu(float v) { return v > 0.f ? v : LRELU_S * v; }

// ============ h = [x | next_demand] ============
__global__ __launch_bounds__(256) void k_concat_h(const float* __restrict__ x,
    const float* __restrict__ nd, float* __restrict__ h, int total) {
  int t = blockIdx.x * 256 + threadIdx.x;
  if (t >= total) return;
  int n = t >> 6, j = t & 63;
  h[t] = (j < 63) ? x[n * 63 + j] : nd[n];
}

// ============ CSR build ============
__global__ __launch_bounds__(256) void k_deg(const int* __restrict__ ei,
    int* __restrict__ degF, int* __restrict__ degR, int E) {
  int e = blockIdx.x * 256 + threadIdx.x;
  if (e >= E) return;
  int a = ei[e], b = ei[E + e];
  atomicAdd(degF + b, 1);
  atomicAdd(degR + a, 1);
}

__global__ __launch_bounds__(256) void k_scan(const int* __restrict__ deg,
    int* __restrict__ start, int* __restrict__ cur, int n) {
  __shared__ int part[256];
  int chunk = (n + 255) / 256;
  int t = threadIdx.x;
  int lo = t * chunk, hi = min(lo + chunk, n);
  int s = 0;
  for (int i = lo; i < hi; i++) s += deg[i] + 1;
  part[t] = s;
  __syncthreads();
  if (t == 0) {
    int acc = 0;
    for (int i = 0; i < 256; i++) { int v = part[i]; part[i] = acc; acc += v; }
    start[n] = acc;
  }
  __syncthreads();
  int acc = part[t];
  for (int i = lo; i < hi; i++) {
    start[i] = acc; cur[i] = acc;
    acc += deg[i] + 1;
  }
}

__global__ __launch_bounds__(256) void k_scatter(const int* __restrict__ ei,
    int* __restrict__ curF, int* __restrict__ curR,
    int* __restrict__ csrF, int* __restrict__ csrR, int E) {
  int e = blockIdx.x * 256 + threadIdx.x;
  if (e >= E) return;
  int a = ei[e], b = ei[E + e];
  int pf = atomicAdd(curF + b, 1); csrF[pf] = a;
  int pr = atomicAdd(curR + a, 1); csrR[pr] = b;
}

__global__ __launch_bounds__(256) void k_self(const int* __restrict__ startF,
    const int* __restrict__ startR, int* __restrict__ csrF, int* __restrict__ csrR, int n) {
  int d = blockIdx.x * 256 + threadIdx.x;
  if (d >= n) return;
  csrF[startF[d + 1] - 1] = d;
  csrR[startR[d + 1] - 1] = d;
}

// ============ node gemm ============
template<int K, int F>
__global__ __launch_bounds__(256) void k_node_gemm(const float* __restrict__ in,
    const float* __restrict__ Wl, const float* __restrict__ Wr,
    float* __restrict__ xl, float* __restrict__ xr, int n) {
  __shared__ float sx[32][K + 1];
  const int row0 = blockIdx.x * 32;
  const float* __restrict__ W = blockIdx.y ? Wr : Wl;
  float* __restrict__ out = blockIdx.y ? xr : xl;
  const int tid = threadIdx.x;
  for (int i = tid; i < 32 * K; i += 256) {
    int r = i / K, c = i - r * K;
    sx[r][c] = (row0 + r < n) ? in[(size_t)(row0 + r) * K + c] : 0.f;
  }
  __syncthreads();
  const int nl = tid & 31;
  const int fg = tid >> 5;
  const int row = row0 + nl;
  if (row >= n) return;
  constexpr int FP = F / 8;
  for (int i = 0; i < FP; i++) {
    int f = fg * FP + i;
    const float* __restrict__ wrow = W + (size_t)f * K;
    float acc = 0.f;
    #pragma unroll
    for (int k = 0; k < K; k += 4) {
      float4 wv = *(const float4*)(wrow + k);
      acc += sx[nl][k] * wv.x + sx[nl][k + 1] * wv.y
           + sx[nl][k + 2] * wv.z + sx[nl][k + 3] * wv.w;
    }
    out[(size_t)row * F + f] = acc;
  }
}

// ============ fused GATv2 edge pass ============
template<int HF, int C>
__global__ __launch_bounds__(256) void k_gat_fused(const float* __restrict__ XL,
    const float* __restrict__ XR, const float* __restrict__ att,
    const float* __restrict__ bias, const int* __restrict__ start,
    const int* __restrict__ csr, float* __restrict__ out, int n) {
  constexpr int DPB = 256 / HF;
  int d = blockIdx.x * DPB + threadIdx.x / HF;
  if (d >= n) return;
  int f = threadIdx.x & (HF - 1);
  float xr = XR[(size_t)d * HF + f];
  float av = att[f];
  float m = -INFINITY, den = 0.f, acc = 0.f;
  int j1 = start[d + 1];
  for (int j = start[d]; j < j1; j++) {
    int s = csr[j];
    float xl = XL[(size_t)s * HF + f];
    float e = xl + xr;
    e = e > 0.f ? e : LRELU_S * e;
    float partial = av * e;
    #pragma unroll
    for (int o = C / 2; o > 0; o >>= 1) partial += __shfl_xor(partial, o, 64);
    float sc = partial;
    float mn = fmaxf(m, sc);
    float scale = expf(m - mn);
    float p = expf(sc - mn);
    den = den * scale + p;
    acc = acc * scale + p * xl;
    m = mn;
  }
  out[(size_t)d * HF + f] = lrelu(acc / (den + 1e-16f) + bias[f]);
}

// ============ s = [xf | xb] -> bf16 ============
__global__ __launch_bounds__(256) void k_concat_s(const float* __restrict__ XF,
    const float* __restrict__ XB, short* __restrict__ SBF, int total) {
  int t = blockIdx.x * 256 + threadIdx.x;
  if (t >= total) return;
  int n = t >> 7, j = t & 127;
  float v = (j < 64) ? XF[n * 64 + j] : XB[n * 64 + (j - 64)];
  SBF[t] = f2bf(v);
}

// ============ weights -> bf16, fragment-tile packed ============
// Tile = 16 n-rows x 32 k, stored in MFMA B-fragment lane order:
// packed[tile][lane*8+j] = W[nt*16 + (lane&15)][kk*32 + (lane>>4)*8 + j]
// layer1 (Wfc 512x256): tiles 0..255,   tile = nt*8 + kk   (nt 0..31, kk 0..7)
// layer2 (Wfc1 256x512): tiles 256..511, tile-256 = nt*16+kk (nt 0..15, kk 0..15)
// layer3 (Wms 32x256):  tiles 512..527, tile-512 = nt*8 + kk (nt 0..1,  kk 0..7)
__global__ __launch_bounds__(256) void k_wconv(const float* __restrict__ Wfc,
    const float* __restrict__ Wfc1, const float* __restrict__ Wmu,
    const float* __restrict__ Wstd, short* __restrict__ WBF) {
  int t = blockIdx.x * 256 + threadIdx.x;
  if (t >= 270336) return;
  int tile = t >> 9, pos = t & 511;
  int lane = pos >> 3, j = pos & 7;
  int lr = lane & 15, lg = lane >> 4;
  float v;
  if (tile < 256) {
    int nt = tile >> 3, kk = tile & 7;
    v = Wfc[(nt * 16 + lr) * 256 + kk * 32 + lg * 8 + j];
  } else if (tile < 512) {
    int t2 = tile - 256;
    int nt = t2 >> 4, kk = t2 & 15;
    v = Wfc1[(nt * 16 + lr) * 512 + kk * 32 + lg * 8 + j];
  } else {
    int t3 = tile - 512;
    int nt = t3 >> 3, kk = t3 & 7;
    int r = nt * 16 + lr;
    int col = kk * 32 + lg * 8 + j;
    v = (r < 16) ? Wmu[r * 256 + col] : Wstd[(r - 16) * 256 + col];
  }
  WBF[t] = f2bf(v);
}

// ============ fused MLP head: 32 edges / block, 512 threads, bf16 MFMA ============
__device__ __forceinline__ short8 lds_frag(const char* base, int row, int strideB, int k0, int lg) {
  int off = row * strideB + (((k0 * 2) + lg * 16) ^ ((row & 7) << 4));
  return *(const short8*)(base + off);
}

__global__ __launch_bounds__(512, 6) void k_head(
    const short* __restrict__ SBF, const short* __restrict__ WBF,
    const int* __restrict__ ei, const float* __restrict__ epsg,
    const float* __restrict__ b_fc, const float* __restrict__ b_fc1,
    const float* __restrict__ b_mu, const float* __restrict__ b_std,
    float* __restrict__ out, double* __restrict__ LP, int E) {
  __shared__ __align__(16) char lX[16384];   // X [32][256] bf16 swizzled; reused as H2
  __shared__ __align__(16) char lH1[32768];  // H1 [32][512] bf16 swizzled; reused as lMS/lred
  float* lMS  = (float*)lH1;                 // [32*32], valid after layer-2 reads complete
  float* lred = (float*)(lH1 + 4096);        // [8]

  const int tid = threadIdx.x;
  const int eg0 = blockIdx.x * 32;

  // gather X rows = [s[e0] | s[e1]] with write-side swizzle
  for (int q = tid; q < 1024; q += 512) {
    int le = q >> 5, c = q & 31;
    int eg = eg0 + le;
    int node = (c < 16) ? ei[eg] : ei[E + eg];
    const short* srcp = SBF + (size_t)node * 128 + (c & 15) * 8;
    int4 v = *(const int4*)srcp;
    int col = (c * 16) ^ ((le & 7) << 4);
    *(int4*)(lX + le * 512 + col) = v;
  }
  __syncthreads();

  const int w = tid >> 6, lane = tid & 63;
  const int lr = lane & 15, lg = lane >> 4;
  const floatx4 zero = {0.f, 0.f, 0.f, 0.f};

  // ---- layer 1: X[32,256] @ Wfc^T -> H1[32,512]; wave w covers n in [w*64, w*64+64)
  floatx4 acc1[2][4];
  #pragma unroll
  for (int mi = 0; mi < 2; mi++)
    #pragma unroll
    for (int ni = 0; ni < 4; ni++) acc1[mi][ni] = zero;
  for (int kk = 0; kk < 8; kk++) {
    int k0 = kk * 32;
    short8 a0 = lds_frag(lX, lr, 512, k0, lg);
    short8 a1 = lds_frag(lX, 16 + lr, 512, k0, lg);
    #pragma unroll
    for (int ni = 0; ni < 4; ni++) {
      int tile = (w * 4 + ni) * 8 + kk;
      short8 b = *(const short8*)(WBF + tile * 512 + lane * 8);
      acc1[0][ni] = __builtin_amdgcn_mfma_f32_16x16x32_bf16(a0, b, acc1[0][ni], 0, 0, 0);
      acc1[1][ni] = __builtin_amdgcn_mfma_f32_16x16x32_bf16(a1, b, acc1[1][ni], 0, 0, 0);
    }
  }
  #pragma unroll
  for (int mi = 0; mi < 2; mi++)
    #pragma unroll
    for (int ni = 0; ni < 4; ni++) {
      int coln = w * 64 + ni * 16 + lr;
      float bv = b_fc[coln];
      #pragma unroll
      for (int j = 0; j < 4; j++) {
        int row = mi * 16 + lg * 4 + j;
        float v = acc1[mi][ni][j] + bv;
        v = v > 0.f ? v : 0.f;
        *(short*)(lH1 + row * 1024 + ((coln * 2) ^ ((row & 7) << 4))) = f2bf(v);
      }
    }
  __syncthreads();

  // ---- layer 2: H1[32,512] @ Wfc1^T -> H2[32,256]; wave w covers n in [w*32, w*32+32)
  floatx4 acc2[2][2];
  #pragma unroll
  for (int mi = 0; mi < 2; mi++)
    #pragma unroll
    for (int ni = 0; ni < 2; ni++) acc2[mi][ni] = zero;
  for (int kk = 0; kk < 16; kk++) {
    int k0 = kk * 32;
    short8 a0 = lds_frag(lH1, lr, 1024, k0, lg);
    short8 a1 = lds_frag(lH1, 16 + lr, 1024, k0, lg);
    #pragma unroll
    for (int ni = 0; ni < 2; ni++) {
      int tile = 256 + (w * 2 + ni) * 16 + kk;
      short8 b = *(const short8*)(WBF + tile * 512 + lane * 8);
      acc2[0][ni] = __builtin_amdgcn_mfma_f32_16x16x32_bf16(a0, b, acc2[0][ni], 0, 0, 0);
      acc2[1][ni] = __builtin_amdgcn_mfma_f32_16x16x32_bf16(a1, b, acc2[1][ni], 0, 0, 0);
    }
  }
  // H2 -> lX (lX reads finished at sync after layer 1)
  #pragma unroll
  for (int mi = 0; mi < 2; mi++)
    #pragma unroll
    for (int ni = 0; ni < 2; ni++) {
      int coln = w * 32 + ni * 16 + lr;
      float bv = b_fc1[coln];
      #pragma unroll
      for (int j = 0; j < 4; j++) {
        int row = mi * 16 + lg * 4 + j;
        float v = acc2[mi][ni][j] + bv;
        v = v > 0.f ? v : 0.f;
        *(short*)(lX + row * 512 + ((coln * 2) ^ ((row & 7) << 4))) = f2bf(v);
      }
    }
  __syncthreads();   // all lH1 reads + lX(H2) writes complete; lMS overlay now safe

  // ---- layer 3: H2[32,256] @ Wms^T -> MS[32,32]; waves 0-3 only
  if (w < 4) {
    const int mfr = w & 1, nfr = w >> 1;
    floatx4 acc3 = zero;
    for (int kk = 0; kk < 8; kk++) {
      int k0 = kk * 32;
      short8 a = lds_frag(lX, mfr * 16 + lr, 512, k0, lg);
      int tile = 512 + nfr * 8 + kk;
      short8 b = *(const short8*)(WBF + tile * 512 + lane * 8);
      acc3 = __builtin_amdgcn_mfma_f32_16x16x32_bf16(a, b, acc3, 0, 0, 0);
    }
    int coln = nfr * 16 + lr;
    float bv = (coln < 16) ? b_mu[coln] : b_std[coln - 16];
    #pragma unroll
    for (int j = 0; j < 4; j++) {
      int row = mfr * 16 + lg * 4 + j;
      lMS[row * 32 + coln] = acc3[j] + bv;
    }
  }
  __syncthreads();

  // ---- epilogue: sample, tanh, log-prob partial (1 item / thread)
  int m = tid >> 4, g = tid & 15;
  float mu = lMS[m * 32 + g];
  float sr = lMS[m * 32 + 16 + g];
  float sd = (sr > 20.f) ? sr : log1pf(expf(sr));
  int eg = eg0 + m;
  float ep = epsg[(size_t)eg * 16 + g];
  float action = mu + sd * ep;
  float ra = tanhf(action);
  out[(size_t)eg * 16 + g] = ra;
  float lpsum = -0.5f * ep * ep - logf(sd) - HALF_LOG_2PI - logf(1.f - ra * ra + 1e-7f);
  #pragma unroll
  for (int o = 32; o > 0; o >>= 1) lpsum += __shfl_xor(lpsum, o, 64);
  if (lane == 0) lred[w] = lpsum;
  __syncthreads();
  if (tid == 0) {
    double ssum = 0.0;
    #pragma unroll
    for (int i = 0; i < 8; i++) ssum += (double)lred[i];
    atomicAdd(LP, ssum);
  }
}

__global__ void k_finalize(const double* __restrict__ LP, float* __restrict__ out, int pos) {
  out[pos] = (float)(*LP);
}

// =====================================================================
extern "C" void kernel_launch(void* const* d_in, const int* in_sizes, int n_in,
                              void* d_out, int out_size, void* d_ws, size_t ws_size,
                              hipStream_t stream) {
  const float* x    = (const float*)d_in[0];
  const float* nd   = (const float*)d_in[1];
  const int*   ei   = (const int*)d_in[2];
  const float* epsg = (const float*)d_in[3];
  const float* Wl3 = (const float*)d_in[4];  const float* Wr3 = (const float*)d_in[5];
  const float* att3 = (const float*)d_in[6]; const float* b3 = (const float*)d_in[7];
  const float* Wl4 = (const float*)d_in[8];  const float* Wr4 = (const float*)d_in[9];
  const float* att4 = (const float*)d_in[10]; const float* b4 = (const float*)d_in[11];
  const float* Wl1 = (const float*)d_in[12]; const float* Wr1 = (const float*)d_in[13];
  const float* att1 = (const float*)d_in[14]; const float* b1 = (const float*)d_in[15];
  const float* Wl2 = (const float*)d_in[16]; const float* Wr2 = (const float*)d_in[17];
  const float* att2 = (const float*)d_in[18]; const float* b2 = (const float*)d_in[19];
  const float* W_fc  = (const float*)d_in[20]; const float* b_fc  = (const float*)d_in[21];
  const float* W_fc1 = (const float*)d_in[22]; const float* b_fc1 = (const float*)d_in[23];
  const float* W_mu  = (const float*)d_in[24]; const float* b_mu  = (const float*)d_in[25];
  const float* W_std = (const float*)d_in[26]; const float* b_std = (const float*)d_in[27];

  const int N = in_sizes[0] / 63;
  const int E = in_sizes[2] / 2;
  const int E2 = E + N;
  const size_t NN = (size_t)N;

  char* base = (char*)d_ws;
  auto alloc = [&](size_t bytes) { char* p = base; base += (bytes + 15) & ~(size_t)15; return p; };

  float* bufA = (float*)alloc(NN * 128 * 4);
  float* bufB = (float*)alloc(NN * 128 * 4);
  float* XL   = (float*)alloc(NN * 128 * 4);
  float* XR   = (float*)alloc(NN * 128 * 4);
  float* XBp  = (float*)alloc(NN * 64 * 4);
  float* XFp  = (float*)alloc(NN * 64 * 4);
  int* degF   = (int*)alloc(NN * 4);
  int* degR   = (int*)alloc(NN * 4);
  int* curF   = (int*)alloc(NN * 4);
  int* curR   = (int*)alloc(NN * 4);
  int* startF = (int*)alloc((NN + 1) * 4);
  int* startR = (int*)alloc((NN + 1) * 4);
  int* csrF   = (int*)alloc((size_t)E2 * 4);
  int* csrR   = (int*)alloc((size_t)E2 * 4);
  double* LPp = (double*)alloc(8);
  short* SBF  = (short*)alloc(NN * 128 * 2);
  short* WBF  = (short*)alloc(270336 * 2);

  auto nb = [](int total) { return (total + 255) / 256; };

  // ---- CSR build (both directions)
  hipMemsetAsync(degF, 0, NN * 4, stream);
  hipMemsetAsync(degR, 0, NN * 4, stream);
  k_deg<<<nb(E), 256, 0, stream>>>(ei, degF, degR, E);
  k_scan<<<1, 256, 0, stream>>>(degF, startF, curF, N);
  k_scan<<<1, 256, 0, stream>>>(degR, startR, curR, N);
  k_scatter<<<nb(E), 256, 0, stream>>>(ei, curF, curR, csrF, csrR, E);
  k_self<<<nb(N), 256, 0, stream>>>(startF, startR, csrF, csrR, N);

  k_concat_h<<<nb(N * 64), 256, 0, stream>>>(x, nd, bufA, N * 64);
  k_wconv<<<nb(270336), 256, 0, stream>>>(W_fc, W_fc1, W_mu, W_std, WBF);

  // ---- gat3 (reverse): h[N,64] -> bufB[N,128]
  { dim3 g((N + 31) / 32, 2);
    k_node_gemm<64, 128><<<g, 256, 0, stream>>>(bufA, Wl3, Wr3, XL, XR, N); }
  k_gat_fused<128, 32><<<(N + 1) / 2, 256, 0, stream>>>(XL, XR, att3, b3, startR, csrR, bufB, N);

  // ---- gat4 (reverse): bufB[N,128] -> XB[N,64]
  { dim3 g((N + 31) / 32, 2);
    k_node_gemm<128, 64><<<g, 256, 0, stream>>>(bufB, Wl4, Wr4, XL, XR, N); }
  k_gat_fused<64, 64><<<(N + 3) / 4, 256, 0, stream>>>(XL, XR, att4, b4, startR, csrR, XBp, N);

  // ---- gat1 (forward): XB[N,64] -> bufB[N,128]
  { dim3 g((N + 31) / 32, 2);
    k_node_gemm<64, 128><<<g, 256, 0, stream>>>(XBp, Wl1, Wr1, XL, XR, N); }
  k_gat_fused<128, 32><<<(N + 1) / 2, 256, 0, stream>>>(XL, XR, att1, b1, startF, csrF, bufB, N);

  // ---- gat2 (forward): bufB[N,128] -> XF[N,64]
  { dim3 g((N + 31) / 32, 2);
    k_node_gemm<128, 64><<<g, 256, 0, stream>>>(bufB, Wl2, Wr2, XL, XR, N); }
  k_gat_fused<64, 64><<<(N + 3) / 4, 256, 0, stream>>>(XL, XR, att2, b2, startF, csrF, XFp, N);

  // ---- head
  k_concat_s<<<nb(N * 128), 256, 0, stream>>>(XFp, XBp, SBF, N * 128);
  hipMemsetAsync(LPp, 0, 8, stream);
  k_head<<<E / 32, 512, 0, stream>>>(SBF, WBF, ei, epsg, b_fc, b_fc1, b_mu, b_std,
                                     (float*)d_out, LPp, E);
  k_finalize<<<1, 1, 0, stream>>>(LPp, (float*)d_out, E * 16);
}

// Round 4
// 495.522 us; speedup vs baseline: 8.6162x; 1.2044x over previous
//
#include <hip/hip_runtime.h>
#include <hip/hip_bf16.h>
#include <math.h>

typedef __attribute__((ext_vector_type(8))) short short8;
typedef __attribute__((ext_vector_type(4))) float floatx4;

#define LRELU_S 0.2f
#define HALF_LOG_2PI 0.91893853320467274178f

__device__ __forceinline__ short f2bf(float f) {
  union { float f; unsigned u; } x; x.f = f;
  unsigned r = x.u + 0x7FFFu + ((x.u >> 16) & 1u);
  return (short)(r >> 16);
}
__device__ __forceinline__ float lrelu(float v) { return v > 0.f ? v : LRELU_S * v; }

// ============ h = [x | next_demand] ============
__global__ __launch_bounds__(256) void k_concat_h(const float* __restrict__ x,
    const float* __restrict__ nd, float* __restrict__ h, int total) {
  int t = blockIdx.x * 256 + threadIdx.x;
  if (t >= total) return;
  int n = t >> 6, j = t & 63;
  h[t] = (j < 63) ? x[n * 63 + j] : nd[n];
}

// ============ CSR build ============
__global__ __launch_bounds__(256) void k_deg(const int* __restrict__ ei,
    int* __restrict__ degF, int* __restrict__ degR, int E) {
  int e = blockIdx.x * 256 + threadIdx.x;
  if (e >= E) return;
  int a = ei[e], b = ei[E + e];
  atomicAdd(degF + b, 1);
  atomicAdd(degR + a, 1);
}

__global__ __launch_bounds__(256) void k_scan2(const int* __restrict__ degF,
    int* __restrict__ startF, int* __restrict__ curF,
    const int* __restrict__ degR, int* __restrict__ startR, int* __restrict__ curR, int n) {
  const int* __restrict__ deg = blockIdx.x ? degR : degF;
  int* __restrict__ start = blockIdx.x ? startR : startF;
  int* __restrict__ cur   = blockIdx.x ? curR : curF;
  __shared__ int part[256];
  int chunk = (n + 255) / 256;
  int t = threadIdx.x;
  int lo = t * chunk, hi = min(lo + chunk, n);
  int s = 0;
  for (int i = lo; i < hi; i++) s += deg[i] + 1;
  part[t] = s;
  __syncthreads();
  if (t == 0) {
    int acc = 0;
    for (int i = 0; i < 256; i++) { int v = part[i]; part[i] = acc; acc += v; }
    start[n] = acc;
  }
  __syncthreads();
  int acc = part[t];
  for (int i = lo; i < hi; i++) {
    start[i] = acc; cur[i] = acc;
    acc += deg[i] + 1;
  }
}

__global__ __launch_bounds__(256) void k_scatter(const int* __restrict__ ei,
    int* __restrict__ curF, int* __restrict__ curR,
    int* __restrict__ csrF, int* __restrict__ csrR, int E) {
  int e = blockIdx.x * 256 + threadIdx.x;
  if (e >= E) return;
  int a = ei[e], b = ei[E + e];
  int pf = atomicAdd(curF + b, 1); csrF[pf] = a;
  int pr = atomicAdd(curR + a, 1); csrR[pr] = b;
}

__global__ __launch_bounds__(256) void k_self(const int* __restrict__ startF,
    const int* __restrict__ startR, int* __restrict__ csrF, int* __restrict__ csrR, int n) {
  int d = blockIdx.x * 256 + threadIdx.x;
  if (d >= n) return;
  csrF[startF[d + 1] - 1] = d;
  csrR[startR[d + 1] - 1] = d;
}

// ============ node gemm ============
template<int K, int F>
__global__ __launch_bounds__(256) void k_node_gemm(const float* __restrict__ in,
    const float* __restrict__ Wl, const float* __restrict__ Wr,
    float* __restrict__ xl, float* __restrict__ xr, int n) {
  __shared__ float sx[32][K + 1];
  const int row0 = blockIdx.x * 32;
  const float* __restrict__ W = blockIdx.y ? Wr : Wl;
  float* __restrict__ out = blockIdx.y ? xr : xl;
  const int tid = threadIdx.x;
  for (int i = tid; i < 32 * K; i += 256) {
    int r = i / K, c = i - r * K;
    sx[r][c] = (row0 + r < n) ? in[(size_t)(row0 + r) * K + c] : 0.f;
  }
  __syncthreads();
  const int nl = tid & 31;
  const int fg = tid >> 5;
  const int row = row0 + nl;
  if (row >= n) return;
  constexpr int FP = F / 8;
  for (int i = 0; i < FP; i++) {
    int f = fg * FP + i;
    const float* __restrict__ wrow = W + (size_t)f * K;
    float acc = 0.f;
    #pragma unroll
    for (int k = 0; k < K; k += 4) {
      float4 wv = *(const float4*)(wrow + k);
      acc += sx[nl][k] * wv.x + sx[nl][k + 1] * wv.y
           + sx[nl][k + 2] * wv.z + sx[nl][k + 3] * wv.w;
    }
    out[(size_t)row * F + f] = acc;
  }
}

// ============ fused GATv2 edge pass, 4 features / thread ============
// Group = HF/4 threads per dst; head h = C/4 consecutive lanes.
template<int HF, int C>
__global__ __launch_bounds__(256) void k_gat_fused(const float* __restrict__ XL,
    const float* __restrict__ XR, const float* __restrict__ att,
    const float* __restrict__ bias, const int* __restrict__ start,
    const int* __restrict__ csr, float* __restrict__ out, int n) {
  constexpr int G = HF / 4;
  constexpr int DPB = 256 / G;
  int d = blockIdx.x * DPB + threadIdx.x / G;
  if (d >= n) return;
  int f4 = threadIdx.x & (G - 1);
  float4 xr = *(const float4*)(XR + (size_t)d * HF + f4 * 4);
  float4 av = *(const float4*)(att + f4 * 4);
  float4 bv = *(const float4*)(bias + f4 * 4);
  float m = -INFINITY, den = 0.f;
  float4 acc = {0.f, 0.f, 0.f, 0.f};
  int j1 = start[d + 1];
  for (int j = start[d]; j < j1; j++) {
    int s = csr[j];
    float4 xl = *(const float4*)(XL + (size_t)s * HF + f4 * 4);
    float e0 = xl.x + xr.x; e0 = e0 > 0.f ? e0 : LRELU_S * e0;
    float e1 = xl.y + xr.y; e1 = e1 > 0.f ? e1 : LRELU_S * e1;
    float e2 = xl.z + xr.z; e2 = e2 > 0.f ? e2 : LRELU_S * e2;
    float e3 = xl.w + xr.w; e3 = e3 > 0.f ? e3 : LRELU_S * e3;
    float partial = av.x * e0 + av.y * e1 + av.z * e2 + av.w * e3;
    #pragma unroll
    for (int o = C / 8; o > 0; o >>= 1) partial += __shfl_xor(partial, o, 64);
    float sc = partial;
    float mn = fmaxf(m, sc);
    float scale = expf(m - mn);
    float p = expf(sc - mn);
    den = den * scale + p;
    acc.x = acc.x * scale + p * xl.x;
    acc.y = acc.y * scale + p * xl.y;
    acc.z = acc.z * scale + p * xl.z;
    acc.w = acc.w * scale + p * xl.w;
    m = mn;
  }
  float inv = 1.f / (den + 1e-16f);
  float4 o4;
  o4.x = lrelu(acc.x * inv + bv.x);
  o4.y = lrelu(acc.y * inv + bv.y);
  o4.z = lrelu(acc.z * inv + bv.z);
  o4.w = lrelu(acc.w * inv + bv.w);
  *(float4*)(out + (size_t)d * HF + f4 * 4) = o4;
}

// ============ s = [xf | xb] -> bf16 ============
__global__ __launch_bounds__(256) void k_concat_s(const float* __restrict__ XF,
    const float* __restrict__ XB, short* __restrict__ SBF, int total) {
  int t = blockIdx.x * 256 + threadIdx.x;
  if (t >= total) return;
  int n = t >> 7, j = t & 127;
  float v = (j < 64) ? XF[n * 64 + j] : XB[n * 64 + (j - 64)];
  SBF[t] = f2bf(v);
}

// ============ weights -> bf16, fragment-tile packed ============
// packed[tile][lane*8+j] = W[nt*16 + (lane&15)][kk*32 + (lane>>4)*8 + j]
// layer1 (Wfc 512x256): tiles 0..255,   tile = nt*8 + kk
// layer2 (Wfc1 256x512): tiles 256..511, tile-256 = nt*16 + kk
// layer3 (Wms 32x256):  tiles 512..527, tile-512 = nt*8 + kk
__global__ __launch_bounds__(256) void k_wconv(const float* __restrict__ Wfc,
    const float* __restrict__ Wfc1, const float* __restrict__ Wmu,
    const float* __restrict__ Wstd, short* __restrict__ WBF) {
  int t = blockIdx.x * 256 + threadIdx.x;
  if (t >= 270336) return;
  int tile = t >> 9, pos = t & 511;
  int lane = pos >> 3, j = pos & 7;
  int lr = lane & 15, lg = lane >> 4;
  float v;
  if (tile < 256) {
    int nt = tile >> 3, kk = tile & 7;
    v = Wfc[(nt * 16 + lr) * 256 + kk * 32 + lg * 8 + j];
  } else if (tile < 512) {
    int t2 = tile - 256;
    int nt = t2 >> 4, kk = t2 & 15;
    v = Wfc1[(nt * 16 + lr) * 512 + kk * 32 + lg * 8 + j];
  } else {
    int t3 = tile - 512;
    int nt = t3 >> 3, kk = t3 & 7;
    int r = nt * 16 + lr;
    int col = kk * 32 + lg * 8 + j;
    v = (r < 16) ? Wmu[r * 256 + col] : Wstd[(r - 16) * 256 + col];
  }
  WBF[t] = f2bf(v);
}

// ============ fused MLP head: 64 edges / block, 512 threads, chunked H1 ============
__device__ __forceinline__ short8 lds_frag(const char* base, int row, int strideB, int k0, int lg) {
  int off = row * strideB + (((k0 * 2) + lg * 16) ^ ((row & 7) << 4));
  return *(const short8*)(base + off);
}

__global__ __launch_bounds__(512, 4) void k_head(
    const short* __restrict__ SBF, const short* __restrict__ WBF,
    const int* __restrict__ ei, const float* __restrict__ epsg,
    const float* __restrict__ b_fc, const float* __restrict__ b_fc1,
    const float* __restrict__ b_mu, const float* __restrict__ b_std,
    float* __restrict__ out, double* __restrict__ LP, int E) {
  __shared__ __align__(16) char lX[32768];    // X [64][256] bf16 swizzled; later H2 [64][256]
  __shared__ __align__(16) char cbuf[16384];  // H1 chunk [64][128] bf16; later lMS/lred
  float* lMS  = (float*)cbuf;                 // [64*32]
  float* lred = (float*)(cbuf + 8192);        // [8]

  const int tid = threadIdx.x;
  const int eg0 = blockIdx.x * 64;

  // gather X rows = [s[e0] | s[e1]], write-side swizzle
  for (int q = tid; q < 2048; q += 512) {
    int le = q >> 5, c = q & 31;
    int eg = eg0 + le;
    int node = (c < 16) ? ei[eg] : ei[E + eg];
    const short* srcp = SBF + (size_t)node * 128 + (c & 15) * 8;
    int4 v = *(const int4*)srcp;
    int col = (c * 16) ^ ((le & 7) << 4);
    *(int4*)(lX + le * 512 + col) = v;
  }
  __syncthreads();

  const int w = tid >> 6, lane = tid & 63;
  const int lr = lane & 15, lg = lane >> 4;
  const floatx4 zero = {0.f, 0.f, 0.f, 0.f};

  // layer-2 accumulators persist across chunks: acc2[ni2][mi], ni = 2w+ni2, rows mi*16
  floatx4 acc2[2][4];
  #pragma unroll
  for (int a = 0; a < 2; a++)
    #pragma unroll
    for (int b = 0; b < 4; b++) acc2[a][b] = zero;

  for (int c = 0; c < 4; c++) {
    // ---- layer-1 partial: H1 chunk cols [c*128, c*128+128); wave w owns strip ni=w
    floatx4 acc1[4];
    #pragma unroll
    for (int mi = 0; mi < 4; mi++) acc1[mi] = zero;
    for (int kk = 0; kk < 8; kk++) {
      int tile = (c * 8 + w) * 8 + kk;
      short8 b = *(const short8*)(WBF + tile * 512 + lane * 8);
      #pragma unroll
      for (int mi = 0; mi < 4; mi++) {
        short8 a = lds_frag(lX, mi * 16 + lr, 512, kk * 32, lg);
        acc1[mi] = __builtin_amdgcn_mfma_f32_16x16x32_bf16(a, b, acc1[mi], 0, 0, 0);
      }
    }
    __syncthreads();   // prior chunk's cbuf reads complete
    {
      int cl = w * 16 + lr;              // chunk-local col
      float bv = b_fc[c * 128 + cl];
      #pragma unroll
      for (int mi = 0; mi < 4; mi++)
        #pragma unroll
        for (int j = 0; j < 4; j++) {
          int row = mi * 16 + lg * 4 + j;
          float v = acc1[mi][j] + bv;
          v = v > 0.f ? v : 0.f;
          *(short*)(cbuf + row * 256 + ((cl * 2) ^ ((row & 7) << 4))) = f2bf(v);
        }
    }
    __syncthreads();   // chunk visible

    // ---- layer-2 partial accumulate: K-slice kg = c*4 + kk2
    for (int kk2 = 0; kk2 < 4; kk2++) {
      short8 a[4];
      #pragma unroll
      for (int mi = 0; mi < 4; mi++) a[mi] = lds_frag(cbuf, mi * 16 + lr, 256, kk2 * 32, lg);
      #pragma unroll
      for (int ni2 = 0; ni2 < 2; ni2++) {
        int tile = 256 + (2 * w + ni2) * 16 + (c * 4 + kk2);
        short8 b = *(const short8*)(WBF + tile * 512 + lane * 8);
        #pragma unroll
        for (int mi = 0; mi < 4; mi++)
          acc2[ni2][mi] = __builtin_amdgcn_mfma_f32_16x16x32_bf16(a[mi], b, acc2[ni2][mi], 0, 0, 0);
      }
    }
  }
  __syncthreads();   // all chunk work done; lX (X) and cbuf free

  // ---- H2 = relu(acc2 + b_fc1) -> lX (bf16, swizzled)
  #pragma unroll
  for (int ni2 = 0; ni2 < 2; ni2++) {
    int n = (2 * w + ni2) * 16 + lr;
    float bv = b_fc1[n];
    #pragma unroll
    for (int mi = 0; mi < 4; mi++)
      #pragma unroll
      for (int j = 0; j < 4; j++) {
        int row = mi * 16 + lg * 4 + j;
        float v = acc2[ni2][mi][j] + bv;
        v = v > 0.f ? v : 0.f;
        *(short*)(lX + row * 512 + ((n * 2) ^ ((row & 7) << 4))) = f2bf(v);
      }
  }
  __syncthreads();

  // ---- layer 3: H2[64,256] @ Wms^T -> MS[64,32]; wave w: mfr=w>>1, nfr=w&1
  {
    const int mfr = w >> 1, nfr = w & 1;
    floatx4 acc3 = zero;
    for (int kk = 0; kk < 8; kk++) {
      short8 a = lds_frag(lX, mfr * 16 + lr, 512, kk * 32, lg);
      int tile = 512 + nfr * 8 + kk;
      short8 b = *(const short8*)(WBF + tile * 512 + lane * 8);
      acc3 = __builtin_amdgcn_mfma_f32_16x16x32_bf16(a, b, acc3, 0, 0, 0);
    }
    int coln = nfr * 16 + lr;
    float bv = (coln < 16) ? b_mu[coln] : b_std[coln - 16];
    #pragma unroll
    for (int j = 0; j < 4; j++) {
      int row = mfr * 16 + lg * 4 + j;
      lMS[row * 32 + coln] = acc3[j] + bv;
    }
  }
  __syncthreads();

  // ---- epilogue: sample, tanh, log-prob partial (2 items / thread)
  float lpsum = 0.f;
  #pragma unroll
  for (int it = 0; it < 2; it++) {
    int idx = tid + it * 512;
    int m = idx >> 4, g = idx & 15;
    float mu = lMS[m * 32 + g];
    float sr = lMS[m * 32 + 16 + g];
    float sd = (sr > 20.f) ? sr : log1pf(expf(sr));
    int eg = eg0 + m;
    float ep = epsg[(size_t)eg * 16 + g];
    float action = mu + sd * ep;
    float ra = tanhf(action);
    out[(size_t)eg * 16 + g] = ra;
    lpsum += -0.5f * ep * ep - logf(sd) - HALF_LOG_2PI - logf(1.f - ra * ra + 1e-7f);
  }
  #pragma unroll
  for (int o = 32; o > 0; o >>= 1) lpsum += __shfl_xor(lpsum, o, 64);
  if (lane == 0) lred[w] = lpsum;
  __syncthreads();
  if (tid == 0) {
    double ssum = 0.0;
    #pragma unroll
    for (int i = 0; i < 8; i++) ssum += (double)lred[i];
    atomicAdd(LP, ssum);
  }
}

__global__ void k_finalize(const double* __restrict__ LP, float* __restrict__ out, int pos) {
  out[pos] = (float)(*LP);
}

// =====================================================================
extern "C" void kernel_launch(void* const* d_in, const int* in_sizes, int n_in,
                              void* d_out, int out_size, void* d_ws, size_t ws_size,
                              hipStream_t stream) {
  const float* x    = (const float*)d_in[0];
  const float* nd   = (const float*)d_in[1];
  const int*   ei   = (const int*)d_in[2];
  const float* epsg = (const float*)d_in[3];
  const float* Wl3 = (const float*)d_in[4];  const float* Wr3 = (const float*)d_in[5];
  const float* att3 = (const float*)d_in[6]; const float* b3 = (const float*)d_in[7];
  const float* Wl4 = (const float*)d_in[8];  const float* Wr4 = (const float*)d_in[9];
  const float* att4 = (const float*)d_in[10]; const float* b4 = (const float*)d_in[11];
  const float* Wl1 = (const float*)d_in[12]; const float* Wr1 = (const float*)d_in[13];
  const float* att1 = (const float*)d_in[14]; const float* b1 = (const float*)d_in[15];
  const float* Wl2 = (const float*)d_in[16]; const float* Wr2 = (const float*)d_in[17];
  const float* att2 = (const float*)d_in[18]; const float* b2 = (const float*)d_in[19];
  const float* W_fc  = (const float*)d_in[20]; const float* b_fc  = (const float*)d_in[21];
  const float* W_fc1 = (const float*)d_in[22]; const float* b_fc1 = (const float*)d_in[23];
  const float* W_mu  = (const float*)d_in[24]; const float* b_mu  = (const float*)d_in[25];
  const float* W_std = (const float*)d_in[26]; const float* b_std = (const float*)d_in[27];

  const int N = in_sizes[0] / 63;
  const int E = in_sizes[2] / 2;
  const int E2 = E + N;
  const size_t NN = (size_t)N;

  char* base = (char*)d_ws;
  auto alloc = [&](size_t bytes) { char* p = base; base += (bytes + 15) & ~(size_t)15; return p; };

  float* bufA = (float*)alloc(NN * 128 * 4);
  float* bufB = (float*)alloc(NN * 128 * 4);
  float* XL   = (float*)alloc(NN * 128 * 4);
  float* XR   = (float*)alloc(NN * 128 * 4);
  float* XBp  = (float*)alloc(NN * 64 * 4);
  float* XFp  = (float*)alloc(NN * 64 * 4);
  int* degF   = (int*)alloc(NN * 4);
  int* degR   = (int*)alloc(NN * 4);
  int* curF   = (int*)alloc(NN * 4);
  int* curR   = (int*)alloc(NN * 4);
  int* startF = (int*)alloc((NN + 1) * 4);
  int* startR = (int*)alloc((NN + 1) * 4);
  int* csrF   = (int*)alloc((size_t)E2 * 4);
  int* csrR   = (int*)alloc((size_t)E2 * 4);
  double* LPp = (double*)alloc(8);
  short* SBF  = (short*)alloc(NN * 128 * 2);
  short* WBF  = (short*)alloc(270336 * 2);

  auto nb = [](int total) { return (total + 255) / 256; };

  // ---- CSR build (both directions)
  hipMemsetAsync(degF, 0, NN * 4, stream);
  hipMemsetAsync(degR, 0, NN * 4, stream);
  k_deg<<<nb(E), 256, 0, stream>>>(ei, degF, degR, E);
  k_scan2<<<2, 256, 0, stream>>>(degF, startF, curF, degR, startR, curR, N);
  k_scatter<<<nb(E), 256, 0, stream>>>(ei, curF, curR, csrF, csrR, E);
  k_self<<<nb(N), 256, 0, stream>>>(startF, startR, csrF, csrR, N);

  k_concat_h<<<nb(N * 64), 256, 0, stream>>>(x, nd, bufA, N * 64);
  k_wconv<<<nb(270336), 256, 0, stream>>>(W_fc, W_fc1, W_mu, W_std, WBF);

  // ---- gat3 (reverse): h[N,64] -> bufB[N,128]
  { dim3 g((N + 31) / 32, 2);
    k_node_gemm<64, 128><<<g, 256, 0, stream>>>(bufA, Wl3, Wr3, XL, XR, N); }
  k_gat_fused<128, 32><<<(N + 7) / 8, 256, 0, stream>>>(XL, XR, att3, b3, startR, csrR, bufB, N);

  // ---- gat4 (reverse): bufB[N,128] -> XB[N,64]
  { dim3 g((N + 31) / 32, 2);
    k_node_gemm<128, 64><<<g, 256, 0, stream>>>(bufB, Wl4, Wr4, XL, XR, N); }
  k_gat_fused<64, 64><<<(N + 15) / 16, 256, 0, stream>>>(XL, XR, att4, b4, startR, csrR, XBp, N);

  // ---- gat1 (forward): XB[N,64] -> bufB[N,128]
  { dim3 g((N + 31) / 32, 2);
    k_node_gemm<64, 128><<<g, 256, 0, stream>>>(XBp, Wl1, Wr1, XL, XR, N); }
  k_gat_fused<128, 32><<<(N + 7) / 8, 256, 0, stream>>>(XL, XR, att1, b1, startF, csrF, bufB, N);

  // ---- gat2 (forward): bufB[N,128] -> XF[N,64]
  { dim3 g((N + 31) / 32, 2);
    k_node_gemm<128, 64><<<g, 256, 0, stream>>>(bufB, Wl2, Wr2, XL, XR, N); }
  k_gat_fused<64, 64><<<(N + 15) / 16, 256, 0, stream>>>(XL, XR, att2, b2, startF, csrF, XFp, N);

  // ---- head
  k_concat_s<<<nb(N * 128), 256, 0, stream>>>(XFp, XBp, SBF, N * 128);
  hipMemsetAsync(LPp, 0, 8, stream);
  k_head<<<E / 64, 512, 0, stream>>>(SBF, WBF, ei, epsg, b_fc, b_fc1, b_mu, b_std,
                                     (float*)d_out, LPp, E);
  k_finalize<<<1, 1, 0, stream>>>(LPp, (float*)d_out, E * 16);
}

// Round 5
// 479.560 us; speedup vs baseline: 8.9029x; 1.0333x over previous
//
#include <hip/hip_runtime.h>
#include <hip/hip_bf16.h>
#include <math.h>

typedef __attribute__((ext_vector_type(8))) short short8;
typedef __attribute__((ext_vector_type(4))) float floatx4;

#define LRELU_S 0.2f
#define HALF_LOG_2PI 0.91893853320467274178f

__device__ __forceinline__ short f2bf(float f) {
  union { float f; unsigned u; } x; x.f = f;
  unsigned r = x.u + 0x7FFFu + ((x.u >> 16) & 1u);
  return (short)(r >> 16);
}
__device__ __forceinline__ float lrelu(float v) { return v > 0.f ? v : LRELU_S * v; }
__device__ __forceinline__ float frcp(float v) { return __builtin_amdgcn_rcpf(v); }
__device__ __forceinline__ float ftanh(float x) {
  float e = __expf(2.f * x);
  return 1.f - 2.f * frcp(e + 1.f);
}
// bank-balanced swizzle: writes (rows R0+4*lg+j) hit 4 disjoint octets; reads balanced
__device__ __forceinline__ int swzb(int row) {
  return ((((row >> 2) & 3) << 1) | (row & 1)) << 4;
}

// ============ h = [x | next_demand] ============
__global__ __launch_bounds__(256) void k_concat_h(const float* __restrict__ x,
    const float* __restrict__ nd, float* __restrict__ h, int total) {
  int t = blockIdx.x * 256 + threadIdx.x;
  if (t >= total) return;
  int n = t >> 6, j = t & 63;
  h[t] = (j < 63) ? x[n * 63 + j] : nd[n];
}

// ============ CSR build ============
__global__ __launch_bounds__(256) void k_deg(const int* __restrict__ ei,
    int* __restrict__ degF, int* __restrict__ degR, int E) {
  int e = blockIdx.x * 256 + threadIdx.x;
  if (e >= E) return;
  int a = ei[e], b = ei[E + e];
  atomicAdd(degF + b, 1);
  atomicAdd(degR + a, 1);
}

__global__ __launch_bounds__(256) void k_scan2(const int* __restrict__ degF,
    int* __restrict__ startF, int* __restrict__ curF, int* __restrict__ csrF,
    const int* __restrict__ degR, int* __restrict__ startR, int* __restrict__ curR,
    int* __restrict__ csrR, int n) {
  const int* __restrict__ deg = blockIdx.x ? degR : degF;
  int* __restrict__ start = blockIdx.x ? startR : startF;
  int* __restrict__ cur   = blockIdx.x ? curR : curF;
  int* __restrict__ csr   = blockIdx.x ? csrR : csrF;
  __shared__ int part[256];
  int chunk = (n + 255) / 256;
  int t = threadIdx.x;
  int lo = t * chunk, hi = min(lo + chunk, n);
  int s = 0;
  for (int i = lo; i < hi; i++) s += deg[i] + 1;
  part[t] = s;
  __syncthreads();
  if (t == 0) {
    int acc = 0;
    for (int i = 0; i < 256; i++) { int v = part[i]; part[i] = acc; acc += v; }
    start[n] = acc;
  }
  __syncthreads();
  int acc = part[t];
  for (int i = lo; i < hi; i++) {
    start[i] = acc; cur[i] = acc;
    acc += deg[i] + 1;
    csr[acc - 1] = i;          // self-loop slot at segment end
  }
}

__global__ __launch_bounds__(256) void k_scatter(const int* __restrict__ ei,
    int* __restrict__ curF, int* __restrict__ curR,
    int* __restrict__ csrF, int* __restrict__ csrR, int E) {
  int e = blockIdx.x * 256 + threadIdx.x;
  if (e >= E) return;
  int a = ei[e], b = ei[E + e];
  int pf = atomicAdd(curF + b, 1); csrF[pf] = a;
  int pr = atomicAdd(curR + a, 1); csrR[pr] = b;
}

// ============ node gemm ============
template<int K, int F>
__global__ __launch_bounds__(256) void k_node_gemm(const float* __restrict__ in,
    const float* __restrict__ Wl, const float* __restrict__ Wr,
    float* __restrict__ xl, float* __restrict__ xr, int n) {
  __shared__ float sx[32][K + 1];
  const int row0 = blockIdx.x * 32;
  const float* __restrict__ W = blockIdx.y ? Wr : Wl;
  float* __restrict__ out = blockIdx.y ? xr : xl;
  const int tid = threadIdx.x;
  for (int i = tid; i < 32 * K; i += 256) {
    int r = i / K, c = i - r * K;
    sx[r][c] = (row0 + r < n) ? in[(size_t)(row0 + r) * K + c] : 0.f;
  }
  __syncthreads();
  const int nl = tid & 31;
  const int fg = tid >> 5;
  const int row = row0 + nl;
  if (row >= n) return;
  constexpr int FP = F / 8;
  for (int i = 0; i < FP; i++) {
    int f = fg * FP + i;
    const float* __restrict__ wrow = W + (size_t)f * K;
    float acc = 0.f;
    #pragma unroll
    for (int k = 0; k < K; k += 4) {
      float4 wv = *(const float4*)(wrow + k);
      acc += sx[nl][k] * wv.x + sx[nl][k + 1] * wv.y
           + sx[nl][k + 2] * wv.z + sx[nl][k + 3] * wv.w;
    }
    out[(size_t)row * F + f] = acc;
  }
}

// ============ fused GATv2 edge pass, 4 features / thread ============
// OM: 0 = f32 out only, 1 = f32 + bf16(SBF), 2 = bf16(SBF) only
template<int HF, int C, int OM>
__global__ __launch_bounds__(256) void k_gat_fused(const float* __restrict__ XL,
    const float* __restrict__ XR, const float* __restrict__ att,
    const float* __restrict__ bias, const int* __restrict__ start,
    const int* __restrict__ csr, float* __restrict__ out,
    short* __restrict__ sout, int scol, int n) {
  constexpr int G = HF / 4;
  constexpr int DPB = 256 / G;
  int d = blockIdx.x * DPB + threadIdx.x / G;
  if (d >= n) return;
  int f4 = threadIdx.x & (G - 1);
  float4 xr = *(const float4*)(XR + (size_t)d * HF + f4 * 4);
  float4 av = *(const float4*)(att + f4 * 4);
  float4 bv = *(const float4*)(bias + f4 * 4);
  float m = -INFINITY, den = 0.f;
  float4 acc = {0.f, 0.f, 0.f, 0.f};
  int j1 = start[d + 1];
  for (int j = start[d]; j < j1; j++) {
    int s = csr[j];
    float4 xl = *(const float4*)(XL + (size_t)s * HF + f4 * 4);
    float e0 = xl.x + xr.x; e0 = e0 > 0.f ? e0 : LRELU_S * e0;
    float e1 = xl.y + xr.y; e1 = e1 > 0.f ? e1 : LRELU_S * e1;
    float e2 = xl.z + xr.z; e2 = e2 > 0.f ? e2 : LRELU_S * e2;
    float e3 = xl.w + xr.w; e3 = e3 > 0.f ? e3 : LRELU_S * e3;
    float partial = av.x * e0 + av.y * e1 + av.z * e2 + av.w * e3;
    #pragma unroll
    for (int o = C / 8; o > 0; o >>= 1) partial += __shfl_xor(partial, o, 64);
    float sc = partial;
    float mn = fmaxf(m, sc);
    float scale = __expf(m - mn);
    float p = __expf(sc - mn);
    den = den * scale + p;
    acc.x = acc.x * scale + p * xl.x;
    acc.y = acc.y * scale + p * xl.y;
    acc.z = acc.z * scale + p * xl.z;
    acc.w = acc.w * scale + p * xl.w;
    m = mn;
  }
  float inv = frcp(den + 1e-16f);
  float4 o4;
  o4.x = lrelu(acc.x * inv + bv.x);
  o4.y = lrelu(acc.y * inv + bv.y);
  o4.z = lrelu(acc.z * inv + bv.z);
  o4.w = lrelu(acc.w * inv + bv.w);
  if (OM != 2) *(float4*)(out + (size_t)d * HF + f4 * 4) = o4;
  if (OM != 0) {
    union { short s[4]; int2 v; } u;
    u.s[0] = f2bf(o4.x); u.s[1] = f2bf(o4.y);
    u.s[2] = f2bf(o4.z); u.s[3] = f2bf(o4.w);
    *(int2*)(sout + (size_t)d * 128 + scol + f4 * 4) = u.v;
  }
}

// ============ weights -> bf16, fragment-tile packed ============
__global__ __launch_bounds__(256) void k_wconv(const float* __restrict__ Wfc,
    const float* __restrict__ Wfc1, const float* __restrict__ Wmu,
    const float* __restrict__ Wstd, short* __restrict__ WBF) {
  int t = blockIdx.x * 256 + threadIdx.x;
  if (t >= 270336) return;
  int tile = t >> 9, pos = t & 511;
  int lane = pos >> 3, j = pos & 7;
  int lr = lane & 15, lg = lane >> 4;
  float v;
  if (tile < 256) {
    int nt = tile >> 3, kk = tile & 7;
    v = Wfc[(nt * 16 + lr) * 256 + kk * 32 + lg * 8 + j];
  } else if (tile < 512) {
    int t2 = tile - 256;
    int nt = t2 >> 4, kk = t2 & 15;
    v = Wfc1[(nt * 16 + lr) * 512 + kk * 32 + lg * 8 + j];
  } else {
    int t3 = tile - 512;
    int nt = t3 >> 3, kk = t3 & 7;
    int r = nt * 16 + lr;
    int col = kk * 32 + lg * 8 + j;
    v = (r < 16) ? Wmu[r * 256 + col] : Wstd[(r - 16) * 256 + col];
  }
  WBF[t] = f2bf(v);
}

// ============ fused MLP head: 64 edges / block, 512 threads, chunked H1 ============
__device__ __forceinline__ short8 lds_frag(const char* base, int row, int strideB, int k0, int lg) {
  int off = row * strideB + (((k0 * 2) + lg * 16) ^ swzb(row));
  return *(const short8*)(base + off);
}

__global__ __launch_bounds__(512, 4) void k_head(
    const short* __restrict__ SBF, const short* __restrict__ WBF,
    const int* __restrict__ ei, const float* __restrict__ epsg,
    const float* __restrict__ b_fc, const float* __restrict__ b_fc1,
    const float* __restrict__ b_mu, const float* __restrict__ b_std,
    float* __restrict__ out, double* __restrict__ LP, int E) {
  __shared__ __align__(16) char lX[32768];    // X [64][256] bf16 swizzled; later H2 [64][256]
  __shared__ __align__(16) char cbuf[16384];  // H1 chunk [64][128] bf16; later lMS/lred
  float* lMS  = (float*)cbuf;                 // [64*32]
  float* lred = (float*)(cbuf + 8192);        // [8]

  const int tid = threadIdx.x;
  const int eg0 = blockIdx.x * 64;

  // gather X rows = [s[e0] | s[e1]], write-side swizzle
  for (int q = tid; q < 2048; q += 512) {
    int le = q >> 5, c = q & 31;
    int eg = eg0 + le;
    int node = (c < 16) ? ei[eg] : ei[E + eg];
    const short* srcp = SBF + (size_t)node * 128 + (c & 15) * 8;
    int4 v = *(const int4*)srcp;
    int col = (c * 16) ^ swzb(le);
    *(int4*)(lX + le * 512 + col) = v;
  }
  __syncthreads();

  const int w = tid >> 6, lane = tid & 63;
  const int lr = lane & 15, lg = lane >> 4;
  const floatx4 zero = {0.f, 0.f, 0.f, 0.f};

  // layer-2 accumulators persist across chunks: acc2[ni2][mi]
  floatx4 acc2[2][4];
  #pragma unroll
  for (int a = 0; a < 2; a++)
    #pragma unroll
    for (int b = 0; b < 4; b++) acc2[a][b] = zero;

  for (int c = 0; c < 4; c++) {
    // ---- layer-1 partial: H1 chunk cols [c*128, c*128+128); wave w owns strip ni=w
    floatx4 acc1[4];
    #pragma unroll
    for (int mi = 0; mi < 4; mi++) acc1[mi] = zero;
    for (int kk = 0; kk < 8; kk++) {
      int tile = (c * 8 + w) * 8 + kk;
      short8 b = *(const short8*)(WBF + tile * 512 + lane * 8);
      #pragma unroll
      for (int mi = 0; mi < 4; mi++) {
        short8 a = lds_frag(lX, mi * 16 + lr, 512, kk * 32, lg);
        acc1[mi] = __builtin_amdgcn_mfma_f32_16x16x32_bf16(a, b, acc1[mi], 0, 0, 0);
      }
    }
    __syncthreads();   // prior chunk's cbuf reads complete
    {
      int cl = w * 16 + lr;              // chunk-local col
      float bv = b_fc[c * 128 + cl];
      #pragma unroll
      for (int mi = 0; mi < 4; mi++)
        #pragma unroll
        for (int j = 0; j < 4; j++) {
          int row = mi * 16 + lg * 4 + j;
          float v = acc1[mi][j] + bv;
          v = v > 0.f ? v : 0.f;
          *(short*)(cbuf + row * 256 + ((cl * 2) ^ swzb(row))) = f2bf(v);
        }
    }
    __syncthreads();   // chunk visible

    // ---- layer-2 partial accumulate: K-slice kg = c*4 + kk2
    for (int kk2 = 0; kk2 < 4; kk2++) {
      short8 a[4];
      #pragma unroll
      for (int mi = 0; mi < 4; mi++) a[mi] = lds_frag(cbuf, mi * 16 + lr, 256, kk2 * 32, lg);
      #pragma unroll
      for (int ni2 = 0; ni2 < 2; ni2++) {
        int tile = 256 + (2 * w + ni2) * 16 + (c * 4 + kk2);
        short8 b = *(const short8*)(WBF + tile * 512 + lane * 8);
        #pragma unroll
        for (int mi = 0; mi < 4; mi++)
          acc2[ni2][mi] = __builtin_amdgcn_mfma_f32_16x16x32_bf16(a[mi], b, acc2[ni2][mi], 0, 0, 0);
      }
    }
  }
  __syncthreads();   // all chunk work done; lX (X) and cbuf free

  // ---- H2 = relu(acc2 + b_fc1) -> lX (bf16, swizzled)
  #pragma unroll
  for (int ni2 = 0; ni2 < 2; ni2++) {
    int n = (2 * w + ni2) * 16 + lr;
    float bv = b_fc1[n];
    #pragma unroll
    for (int mi = 0; mi < 4; mi++)
      #pragma unroll
      for (int j = 0; j < 4; j++) {
        int row = mi * 16 + lg * 4 + j;
        float v = acc2[ni2][mi][j] + bv;
        v = v > 0.f ? v : 0.f;
        *(short*)(lX + row * 512 + ((n * 2) ^ swzb(row))) = f2bf(v);
      }
  }
  __syncthreads();

  // ---- layer 3: H2[64,256] @ Wms^T -> MS[64,32]; wave w: mfr=w>>1, nfr=w&1
  {
    const int mfr = w >> 1, nfr = w & 1;
    floatx4 acc3 = zero;
    for (int kk = 0; kk < 8; kk++) {
      short8 a = lds_frag(lX, mfr * 16 + lr, 512, kk * 32, lg);
      int tile = 512 + nfr * 8 + kk;
      short8 b = *(const short8*)(WBF + tile * 512 + lane * 8);
      acc3 = __builtin_amdgcn_mfma_f32_16x16x32_bf16(a, b, acc3, 0, 0, 0);
    }
    int coln = nfr * 16 + lr;
    float bv = (coln < 16) ? b_mu[coln] : b_std[coln - 16];
    #pragma unroll
    for (int j = 0; j < 4; j++) {
      int row = mfr * 16 + lg * 4 + j;
      lMS[row * 32 + coln] = acc3[j] + bv;
    }
  }
  __syncthreads();

  // ---- epilogue: sample, tanh, log-prob partial (2 items / thread), fast math
  float lpsum = 0.f;
  #pragma unroll
  for (int it = 0; it < 2; it++) {
    int idx = tid + it * 512;
    int m = idx >> 4, g = idx & 15;
    float mu = lMS[m * 32 + g];
    float sr = lMS[m * 32 + 16 + g];
    float sd = (sr > 20.f) ? sr : __logf(1.f + __expf(sr));
    int eg = eg0 + m;
    float ep = epsg[(size_t)eg * 16 + g];
    float action = mu + sd * ep;
    float ra = ftanh(action);
    out[(size_t)eg * 16 + g] = ra;
    lpsum += -0.5f * ep * ep - __logf(sd) - HALF_LOG_2PI - __logf(1.f - ra * ra + 1e-7f);
  }
  #pragma unroll
  for (int o = 32; o > 0; o >>= 1) lpsum += __shfl_xor(lpsum, o, 64);
  if (lane == 0) lred[w] = lpsum;
  __syncthreads();
  if (tid == 0) {
    double ssum = 0.0;
    #pragma unroll
    for (int i = 0; i < 8; i++) ssum += (double)lred[i];
    atomicAdd(LP, ssum);
  }
}

__global__ void k_finalize(const double* __restrict__ LP, float* __restrict__ out, int pos) {
  out[pos] = (float)(*LP);
}

// =====================================================================
extern "C" void kernel_launch(void* const* d_in, const int* in_sizes, int n_in,
                              void* d_out, int out_size, void* d_ws, size_t ws_size,
                              hipStream_t stream) {
  const float* x    = (const float*)d_in[0];
  const float* nd   = (const float*)d_in[1];
  const int*   ei   = (const int*)d_in[2];
  const float* epsg = (const float*)d_in[3];
  const float* Wl3 = (const float*)d_in[4];  const float* Wr3 = (const float*)d_in[5];
  const float* att3 = (const float*)d_in[6]; const float* b3 = (const float*)d_in[7];
  const float* Wl4 = (const float*)d_in[8];  const float* Wr4 = (const float*)d_in[9];
  const float* att4 = (const float*)d_in[10]; const float* b4 = (const float*)d_in[11];
  const float* Wl1 = (const float*)d_in[12]; const float* Wr1 = (const float*)d_in[13];
  const float* att1 = (const float*)d_in[14]; const float* b1 = (const float*)d_in[15];
  const float* Wl2 = (const float*)d_in[16]; const float* Wr2 = (const float*)d_in[17];
  const float* att2 = (const float*)d_in[18]; const float* b2 = (const float*)d_in[19];
  const float* W_fc  = (const float*)d_in[20]; const float* b_fc  = (const float*)d_in[21];
  const float* W_fc1 = (const float*)d_in[22]; const float* b_fc1 = (const float*)d_in[23];
  const float* W_mu  = (const float*)d_in[24]; const float* b_mu  = (const float*)d_in[25];
  const float* W_std = (const float*)d_in[26]; const float* b_std = (const float*)d_in[27];

  const int N = in_sizes[0] / 63;
  const int E = in_sizes[2] / 2;
  const int E2 = E + N;
  const size_t NN = (size_t)N;

  char* base = (char*)d_ws;
  auto alloc = [&](size_t bytes) { char* p = base; base += (bytes + 15) & ~(size_t)15; return p; };

  float* bufA = (float*)alloc(NN * 128 * 4);
  float* bufB = (float*)alloc(NN * 128 * 4);
  float* XL   = (float*)alloc(NN * 128 * 4);
  float* XR   = (float*)alloc(NN * 128 * 4);
  float* XBp  = (float*)alloc(NN * 64 * 4);
  int* degF   = (int*)alloc(NN * 4);
  int* degR   = (int*)alloc(NN * 4);
  int* curF   = (int*)alloc(NN * 4);
  int* curR   = (int*)alloc(NN * 4);
  int* startF = (int*)alloc((NN + 1) * 4);
  int* startR = (int*)alloc((NN + 1) * 4);
  int* csrF   = (int*)alloc((size_t)E2 * 4);
  int* csrR   = (int*)alloc((size_t)E2 * 4);
  double* LPp = (double*)alloc(8);
  short* SBF  = (short*)alloc(NN * 128 * 2);
  short* WBF  = (short*)alloc(270336 * 2);

  auto nb = [](int total) { return (total + 255) / 256; };

  // ---- CSR build (both directions); degF/degR contiguous -> one memset
  hipMemsetAsync(degF, 0, NN * 8, stream);
  k_deg<<<nb(E), 256, 0, stream>>>(ei, degF, degR, E);
  k_scan2<<<2, 256, 0, stream>>>(degF, startF, curF, csrF, degR, startR, curR, csrR, N);
  k_scatter<<<nb(E), 256, 0, stream>>>(ei, curF, curR, csrF, csrR, E);

  k_concat_h<<<nb(N * 64), 256, 0, stream>>>(x, nd, bufA, N * 64);
  k_wconv<<<nb(270336), 256, 0, stream>>>(W_fc, W_fc1, W_mu, W_std, WBF);

  // ---- gat3 (reverse): h[N,64] -> bufB[N,128]
  { dim3 g((N + 31) / 32, 2);
    k_node_gemm<64, 128><<<g, 256, 0, stream>>>(bufA, Wl3, Wr3, XL, XR, N); }
  k_gat_fused<128, 32, 0><<<(N + 7) / 8, 256, 0, stream>>>(XL, XR, att3, b3, startR, csrR, bufB, nullptr, 0, N);

  // ---- gat4 (reverse): bufB[N,128] -> XB[N,64] (+ bf16 into SBF cols 64..128)
  { dim3 g((N + 31) / 32, 2);
    k_node_gemm<128, 64><<<g, 256, 0, stream>>>(bufB, Wl4, Wr4, XL, XR, N); }
  k_gat_fused<64, 64, 1><<<(N + 15) / 16, 256, 0, stream>>>(XL, XR, att4, b4, startR, csrR, XBp, SBF, 64, N);

  // ---- gat1 (forward): XB[N,64] -> bufB[N,128]
  { dim3 g((N + 31) / 32, 2);
    k_node_gemm<64, 128><<<g, 256, 0, stream>>>(XBp, Wl1, Wr1, XL, XR, N); }
  k_gat_fused<128, 32, 0><<<(N + 7) / 8, 256, 0, stream>>>(XL, XR, att1, b1, startF, csrF, bufB, nullptr, 0, N);

  // ---- gat2 (forward): bufB[N,128] -> bf16 SBF cols 0..64 only
  { dim3 g((N + 31) / 32, 2);
    k_node_gemm<128, 64><<<g, 256, 0, stream>>>(bufB, Wl2, Wr2, XL, XR, N); }
  k_gat_fused<64, 64, 2><<<(N + 15) / 16, 256, 0, stream>>>(XL, XR, att2, b2, startF, csrF, nullptr, SBF, 0, N);

  // ---- head
  hipMemsetAsync(LPp, 0, 8, stream);
  k_head<<<E / 64, 512, 0, stream>>>(SBF, WBF, ei, epsg, b_fc, b_fc1, b_mu, b_std,
                                     (float*)d_out, LPp, E);
  k_finalize<<<1, 1, 0, stream>>>(LPp, (float*)d_out, E * 16);
}